// Round 4
// baseline (235.018 us; speedup 1.0000x reference)
//
#include <hip/hip_runtime.h>
#include <cstdint>

typedef uint16_t u16;
typedef __attribute__((ext_vector_type(8))) short bf16x8;
typedef __attribute__((ext_vector_type(4))) short bf16x4;
typedef __attribute__((ext_vector_type(4))) float f32x4;

// 0.125 * log2(e): folded into Q projection so softmax is exp2(s) directly.
#define QSCALE 0.18033688011112042f

struct Ptr3 { const float* a; const float* b; const float* c; };

__device__ __forceinline__ u16 f2bf(float x) {
  union { float f; uint32_t u; } v; v.f = x;
  uint32_t r = (v.u + 0x7fffu + ((v.u >> 16) & 1u)) >> 16;
  return (u16)r;
}

// packed f32x2 -> bf16x2 (low = a, high = b). gfx950 has a HW instruction.
#if __has_builtin(__builtin_amdgcn_cvt_pk_bf16_f32)
typedef __bf16 bf2_t __attribute__((ext_vector_type(2)));
__device__ __forceinline__ uint32_t pkbf(float a, float b) {
  bf2_t v = __builtin_amdgcn_cvt_pk_bf16_f32(a, b);
  uint32_t u;
  __builtin_memcpy(&u, &v, 4);
  return u;
}
#else
__device__ __forceinline__ uint32_t pkbf(float a, float b) {
  return (uint32_t)f2bf(a) | ((uint32_t)f2bf(b) << 16);
}
#endif

// async global->LDS, 16B per lane. LDS dest is wave-uniform base + lane*16.
__device__ __forceinline__ void async16(void* lds, const void* g) {
  __builtin_amdgcn_global_load_lds((const __attribute__((address_space(1))) void*)g,
                                   (__attribute__((address_space(3))) void*)lds, 16, 0, 0);
}

// -------- fused pre-pass: input casts (12288 blocks) + weight transposes ---
// bx<12288: f32->bf16 cast of q/k/v. bx>=12288: 1024 transpose blocks
// (768 for Wq/Wk/Wv -> wt[w][h*64+k][d], 256 for out_w (KxN) -> wto (NxK)).
__global__ __launch_bounds__(256) void k_prep(Ptr3 in, u16* __restrict__ out,
                                              Ptr3 w, const float* __restrict__ ow,
                                              u16* __restrict__ wt, u16* __restrict__ wto) {
  __shared__ u16 tile[64 * 65];
  const int t = threadIdx.x;
  const int bx = blockIdx.x;
  if (bx < 12288) {
    int z = bx >> 12;
    int i = (bx & 4095) * 256 + t;
    const float* p = z == 0 ? in.a : (z == 1 ? in.b : in.c);
    float4 v = ((const float4*)p)[i];
    uint2 o2;
    o2.x = pkbf(v.x, v.y);
    o2.y = pkbf(v.z, v.w);
    *(uint2*)(out + (long)z * 4194304 + (long)i * 4) = o2;
    return;
  }
  const int b2 = bx - 12288;
  const float* src;
  long in_base, out_base;
  int rstr, r0, c0;
  u16* outp;
  if (b2 < 768) {
    int z = b2 >> 4;
    r0 = (b2 & 15) * 64; c0 = 0;
    src = (z < 16) ? w.a : (z < 32 ? w.b : w.c);
    in_base = (long)(z & 15) * 65536;
    out_base = (long)z * 65536;
    rstr = 64; outp = wt;
  } else {
    int idx = b2 - 768;
    r0 = (idx >> 4) * 64; c0 = (idx & 15) * 64;
    src = ow; in_base = 0; out_base = 0;
    rstr = 1024; outp = wto;
  }
  for (int e = t; e < 4096; e += 256) {
    int rr = e >> 6, cc = e & 63;
    tile[rr * 65 + cc] = f2bf(src[in_base + (long)(r0 + rr) * rstr + c0 + cc]);
  }
  __syncthreads();
  for (int s = t; s < 512; s += 256) {
    int cc = s >> 3, r8 = (s & 7) << 3;
    bf16x8 p;
    #pragma unroll
    for (int j = 0; j < 8; ++j) p[j] = (short)tile[(r8 + j) * 65 + cc];
    *(bf16x8*)(outp + out_base + (long)(c0 + cc) * 1024 + r0 + r8) = p;
  }
}

// ---------------- fused QKV GEMM: 128x128 tile, BK=64, grid (8,32,3) -------
// (R2-verbatim)
__global__ __launch_bounds__(256) void k_gemm_qkv(const u16* __restrict__ A0,
                                                  const u16* __restrict__ B0,
                                                  u16* __restrict__ C0,
                                                  u16* __restrict__ Vt, float scale0) {
  __shared__ __align__(16) u16 smem[16640];   // As[0:8192) Bs[8192:16384) T[0:16640)
  u16* As = smem;
  u16* Bs = smem + 8192;
  u16* T  = smem;                             // z==2 epilogue only (128 x 130)
  const int z = blockIdx.z;
  const u16* A = A0 + (long)z * 4194304;
  const u16* Bt = B0 + (long)z * 1048576;
  const int t = threadIdx.x, lane = t & 63, quad = lane >> 4, l16 = lane & 15;
  const int wave = t >> 6, wy = wave >> 1, wx = wave & 1;
  const int m0 = blockIdx.y * 128, n0 = blockIdx.x * 128;
  const int wbase = t & 192;
  f32x4 acc[4][4] = {};
  for (int k0 = 0; k0 < 1024; k0 += 64) {
    __syncthreads();
    #pragma unroll
    for (int i = 0; i < 4; ++i) {
      int sb = i * 256 + wbase;
      int s = sb + lane;
      int row = s >> 3, c = s & 7;
      int cs = c ^ (row & 7);              // source chunk for LDS pos c
      async16(As + sb * 8, A + (long)(m0 + row) * 1024 + k0 + cs * 8);
      async16(Bs + sb * 8, Bt + (long)(n0 + row) * 1024 + k0 + cs * 8);
    }
    __syncthreads();
    #pragma unroll
    for (int kk = 0; kk < 2; ++kk) {
      bf16x8 af[4], bfr[4];
      #pragma unroll
      for (int mt = 0; mt < 4; ++mt) {
        int row = wy * 64 + mt * 16 + l16;
        int pos = (kk * 4 + quad) ^ (row & 7);
        af[mt] = *(const bf16x8*)(As + row * 64 + pos * 8);
      }
      #pragma unroll
      for (int nt = 0; nt < 4; ++nt) {
        int row = wx * 64 + nt * 16 + l16;
        int pos = (kk * 4 + quad) ^ (row & 7);
        bfr[nt] = *(const bf16x8*)(Bs + row * 64 + pos * 8);
      }
      #pragma unroll
      for (int mt = 0; mt < 4; ++mt)
        #pragma unroll
        for (int nt = 0; nt < 4; ++nt)
          acc[mt][nt] = __builtin_amdgcn_mfma_f32_16x16x32_bf16(af[mt], bfr[nt], acc[mt][nt], 0, 0, 0);
    }
  }
  if (z < 2) {
    u16* C = C0 + (long)z * 4194304;
    const float scale = z ? 1.0f : scale0;
    #pragma unroll
    for (int mt = 0; mt < 4; ++mt)
      #pragma unroll
      for (int nt = 0; nt < 4; ++nt) {
        int col = n0 + wx * 64 + nt * 16 + l16;
        int row = m0 + wy * 64 + mt * 16 + quad * 4;
        uint32_t ua = pkbf(acc[mt][nt][0] * scale, acc[mt][nt][1] * scale);
        uint32_t ub = pkbf(acc[mt][nt][2] * scale, acc[mt][nt][3] * scale);
        C[(long)row * 1024 + col] = (u16)ua;
        C[(long)(row + 1) * 1024 + col] = (u16)(ua >> 16);
        C[(long)(row + 2) * 1024 + col] = (u16)ub;
        C[(long)(row + 3) * 1024 + col] = (u16)(ub >> 16);
      }
  } else {
    __syncthreads();  // all waves done reading As/Bs before T overlays them
    #pragma unroll
    for (int mt = 0; mt < 4; ++mt)
      #pragma unroll
      for (int nt = 0; nt < 4; ++nt) {
        int cc = wx * 64 + nt * 16 + l16;
        int rr = wy * 64 + mt * 16 + quad * 4;
        uint32_t ua = pkbf(acc[mt][nt][0], acc[mt][nt][1]);
        uint32_t ub = pkbf(acc[mt][nt][2], acc[mt][nt][3]);
        T[(rr + 0) * 130 + cc] = (u16)ua;
        T[(rr + 1) * 130 + cc] = (u16)(ua >> 16);
        T[(rr + 2) * 130 + cc] = (u16)ub;
        T[(rr + 3) * 130 + cc] = (u16)(ub >> 16);
      }
    __syncthreads();
    const int h0 = blockIdx.x * 2, bb = m0 >> 11, lb = m0 & 2047;
    #pragma unroll
    for (int i = 0; i < 8; ++i) {
      int s = t + i * 256;           // 0..2047 = 128 cols x 16 l-chunks
      int c = s >> 4, l0 = (s & 15) * 8;
      bf16x8 p;
      #pragma unroll
      for (int j = 0; j < 8; ++j) p[j] = (short)T[(l0 + j) * 130 + c];
      *(bf16x8*)(Vt + (long)(bb * 16 + h0 + (c >> 6)) * 131072 +
                 (long)(c & 63) * 2048 + lb + l0) = p;
    }
  }
}

// ---- out-proj GEMM: NEW 128x128 tile, BK=64, grid (8,32) — port of the ----
// proven k_gemm_qkv K-loop (16 MFMA/barrier-pair vs old 8 at BK=32, half
// the barrier count). Epilogue: f32 + bias.
__global__ __launch_bounds__(256) void k_gemm_out(const u16* __restrict__ A,
                                                  const u16* __restrict__ Bt,
                                                  float* __restrict__ C,
                                                  const float* __restrict__ bias) {
  __shared__ __align__(16) u16 smem[16384];   // As[0:8192) Bs[8192:16384)
  u16* As = smem;
  u16* Bs = smem + 8192;
  const int t = threadIdx.x, lane = t & 63, quad = lane >> 4, l16 = lane & 15;
  const int wave = t >> 6, wy = wave >> 1, wx = wave & 1;
  const int m0 = blockIdx.y * 128, n0 = blockIdx.x * 128;
  const int wbase = t & 192;
  f32x4 acc[4][4] = {};
  for (int k0 = 0; k0 < 1024; k0 += 64) {
    __syncthreads();
    #pragma unroll
    for (int i = 0; i < 4; ++i) {
      int sb = i * 256 + wbase;
      int s = sb + lane;
      int row = s >> 3, c = s & 7;
      int cs = c ^ (row & 7);              // source chunk for LDS pos c
      async16(As + sb * 8, A + (long)(m0 + row) * 1024 + k0 + cs * 8);
      async16(Bs + sb * 8, Bt + (long)(n0 + row) * 1024 + k0 + cs * 8);
    }
    __syncthreads();
    #pragma unroll
    for (int kk = 0; kk < 2; ++kk) {
      bf16x8 af[4], bfr[4];
      #pragma unroll
      for (int mt = 0; mt < 4; ++mt) {
        int row = wy * 64 + mt * 16 + l16;
        int pos = (kk * 4 + quad) ^ (row & 7);
        af[mt] = *(const bf16x8*)(As + row * 64 + pos * 8);
      }
      #pragma unroll
      for (int nt = 0; nt < 4; ++nt) {
        int row = wx * 64 + nt * 16 + l16;
        int pos = (kk * 4 + quad) ^ (row & 7);
        bfr[nt] = *(const bf16x8*)(Bs + row * 64 + pos * 8);
      }
      #pragma unroll
      for (int mt = 0; mt < 4; ++mt)
        #pragma unroll
        for (int nt = 0; nt < 4; ++nt)
          acc[mt][nt] = __builtin_amdgcn_mfma_f32_16x16x32_bf16(af[mt], bfr[nt], acc[mt][nt], 0, 0, 0);
    }
  }
  #pragma unroll
  for (int nt = 0; nt < 4; ++nt) {
    int col = n0 + wx * 64 + nt * 16 + l16;
    float bv = bias[col];
    #pragma unroll
    for (int mt = 0; mt < 4; ++mt) {
      int row = m0 + wy * 64 + mt * 16 + quad * 4;
      C[(long)row * 1024 + col]       = acc[mt][nt][0] + bv;
      C[(long)(row + 1) * 1024 + col] = acc[mt][nt][1] + bv;
      C[(long)(row + 2) * 1024 + col] = acc[mt][nt][2] + bv;
      C[(long)(row + 3) * 1024 + col] = acc[mt][nt][3] + bv;
    }
  }
}

// ------- flash attention (R2 compute body, double-buffered K/V, 1 barrier) -
// 512 threads, q-tile 256, grid 256 = 1 block/CU. The msub compute phase
// (swapped QK -> S^T, b64 P-store, PV) is R2-verbatim — proven 57.4us.
// THIS round: ks/vs double-buffered (+18KB) so the per-kt hazard needs ONE
// barrier instead of two (iteration kt reads buf[kt&1], writes prefetch to
// buf[(kt+1)&1]; reads of a buffer always complete an iteration before it is
// rewritten). To fit 64KB LDS, P gets a dedicated 18KB array and the
// one-time Q fragment load goes direct from global (L2-resident).
__global__ __launch_bounds__(512, 2) void k_flash(const u16* __restrict__ Qp,
                                                  const u16* __restrict__ Kp,
                                                  const u16* __restrict__ Vt,
                                                  u16* __restrict__ ctx) {
  __shared__ __align__(16) u16 ks[2][4608];    // 2 x (64 x 72) K tiles
  __shared__ __align__(16) u16 vs[2][4608];    // 2 x (64 x 72) V^T tiles
  __shared__ __align__(16) u16 ps[9216];       // 18KB: 8 waves x 16 q x 72
  const int t = threadIdx.x, lane = t & 63, quad = lane >> 4, l16 = lane & 15;
  const int wave = t >> 6;                      // 0..7
  const int bh = blockIdx.x & 31, b = bh >> 4, h = bh & 15;
  const int q0 = (blockIdx.x >> 5) * 256;
  const long gkbase = (long)b * 2097152 + h * 64;
  const long gvbase = (long)bh * 131072;
  const int srow = t >> 3, sc = t & 7;          // staging: row 0..63, 16B chunk 0..7

  // ---- startup: Q fragments direct from global; K/V tile 0 via regs ----
  bf16x8 qf[2][2];
  {
    long gq = (long)(b * 2048 + q0) * 1024 + h * 64;
    #pragma unroll
    for (int msub = 0; msub < 2; ++msub)
      #pragma unroll
      for (int kh = 0; kh < 2; ++kh) {
        int m = wave * 32 + msub * 16 + l16;
        qf[msub][kh] = *(const bf16x8*)(Qp + gq + (long)m * 1024 + kh * 32 + quad * 8);
      }
  }
  {
    bf16x8 k0 = *(const bf16x8*)(Kp + gkbase + (long)srow * 1024 + sc * 8);
    bf16x8 v0 = *(const bf16x8*)(Vt + gvbase + (long)srow * 2048 + sc * 8);
    *(bf16x8*)(&ks[0][srow * 72 + sc * 8]) = k0;
    *(bf16x8*)(&vs[0][srow * 72 + sc * 8]) = v0;
  }
  __syncthreads();  // K/V tile 0 visible

  u16* pw = ps + wave * 1152;  // per-wave P tile: 16 q-rows x 72 (one msub at a time)

  float ls[2] = {};
  f32x4 o[2][4] = {};
  bf16x8 kreg, vreg;

  #pragma unroll 2
  for (int kt = 0; kt < 32; ++kt) {
    const u16* kc = ks[kt & 1];
    const u16* vc = vs[kt & 1];

    // register prefetch of next K/V tile (in flight across this compute phase)
    if (kt < 31) {
      int kv0 = (kt + 1) * 64;
      kreg = *(const bf16x8*)(Kp + gkbase + (long)(kv0 + srow) * 1024 + sc * 8);
      vreg = *(const bf16x8*)(Vt + gvbase + kv0 + (long)srow * 2048 + sc * 8);
    }

    // K and V^T fragments (vector b128, <=2-way banks)
    bf16x8 kf[4][2], vf[4][2];
    #pragma unroll
    for (int nt = 0; nt < 4; ++nt)
      #pragma unroll
      for (int kh = 0; kh < 2; ++kh) {
        kf[nt][kh] = *(const bf16x8*)(kc + (nt * 16 + l16) * 72 + kh * 32 + quad * 8);
        vf[nt][kh] = *(const bf16x8*)(vc + (nt * 16 + l16) * 72 + kh * 32 + quad * 8);
      }

    #pragma unroll
    for (int msub = 0; msub < 2; ++msub) {
      // S^T(64x16) = K @ Q^T ; lane holds S[q=l16][kv=nt*16+quad*4+r].
      // p = exp2(s); one b64 store per nt -> P[q][kv] row-major in LDS.
      #pragma unroll
      for (int nt = 0; nt < 4; ++nt) {
        f32x4 a = {};
        #pragma unroll
        for (int kh = 0; kh < 2; ++kh)
          a = __builtin_amdgcn_mfma_f32_16x16x32_bf16(kf[nt][kh], qf[msub][kh], a, 0, 0, 0);
        float e0 = __builtin_amdgcn_exp2f(a[0]);
        float e1 = __builtin_amdgcn_exp2f(a[1]);
        float e2 = __builtin_amdgcn_exp2f(a[2]);
        float e3 = __builtin_amdgcn_exp2f(a[3]);
        ls[msub] += (e0 + e1) + (e2 + e3);
        uint2 w;
        w.x = pkbf(e0, e1);
        w.y = pkbf(e2, e3);
        *(uint2*)(pw + l16 * 72 + nt * 16 + quad * 4) = w;
      }
      // O(16x64) += P @ V : A-frag = contiguous b128 rows of P (unchanged)
      #pragma unroll
      for (int kh = 0; kh < 2; ++kh) {
        bf16x8 pa = *(const bf16x8*)(pw + l16 * 72 + kh * 32 + quad * 8);
        #pragma unroll
        for (int nt = 0; nt < 4; ++nt)
          o[msub][nt] = __builtin_amdgcn_mfma_f32_16x16x32_bf16(pa, vf[nt][kh], o[msub][nt], 0, 0, 0);
      }
    }

    // write prefetch into the NEXT buffer (nobody reads it this iteration)
    if (kt < 31) {
      u16* kn = ks[(kt + 1) & 1];
      u16* vn = vs[(kt + 1) & 1];
      *(bf16x8*)(&kn[srow * 72 + sc * 8]) = kreg;
      *(bf16x8*)(&vn[srow * 72 + sc * 8]) = vreg;
    }
    __syncthreads();  // next tile visible; current reads all drained
  }

  // final l: reduce over the 4 quads (each lane holds partial for q=l16),
  // reciprocal, then shuffle 1/l to the lanes holding output rows quad*4+r.
  #pragma unroll
  for (int msub = 0; msub < 2; ++msub) {
    float l = ls[msub];
    l += __shfl_xor(l, 16);
    l += __shfl_xor(l, 32);
    float linv = 1.0f / l;                 // valid for q = l16 on every lane
    float li0 = __shfl(linv, quad * 4 + 0);
    float li1 = __shfl(linv, quad * 4 + 1);
    float li2 = __shfl(linv, quad * 4 + 2);
    float li3 = __shfl(linv, quad * 4 + 3);
    #pragma unroll
    for (int nt = 0; nt < 4; ++nt) {
      int q = q0 + wave * 32 + msub * 16 + quad * 4;
      long idx = (long)(b * 2048 + q) * 1024 + h * 64 + nt * 16 + l16;
      uint32_t ua = pkbf(o[msub][nt][0] * li0, o[msub][nt][1] * li1);
      uint32_t ub = pkbf(o[msub][nt][2] * li2, o[msub][nt][3] * li3);
      ctx[idx]        = (u16)ua;
      ctx[idx + 1024] = (u16)(ua >> 16);
      ctx[idx + 2048] = (u16)ub;
      ctx[idx + 3072] = (u16)(ub >> 16);
    }
  }
}

extern "C" void kernel_launch(void* const* d_in, const int* in_sizes, int n_in,
                              void* d_out, int out_size, void* d_ws, size_t ws_size,
                              hipStream_t stream) {
  const float* query = (const float*)d_in[0];
  const float* key   = (const float*)d_in[1];
  const float* value = (const float*)d_in[2];
  const float* Wq    = (const float*)d_in[3];
  const float* Wk    = (const float*)d_in[4];
  const float* Wv    = (const float*)d_in[5];
  const float* out_w = (const float*)d_in[6];
  const float* out_b = (const float*)d_in[7];
  // d_in[8] = coupling: unused — per-head scalar bias is softmax-invariant.
  float* out = (float*)d_out;

  char* ws = (char*)d_ws;
  size_t off = 0;
  auto alloc = [&](size_t bytes) {
    void* p = ws + off;
    off += (bytes + 255) & ~(size_t)255;
    return p;
  };
  // qb,kb,vb contiguous (k_prep cast z-stride); wtq..wtv contiguous
  // (k_prep transpose z-stride); Qp,Kp contiguous (k_gemm_qkv z<2 stride).
  u16* qb  = (u16*)alloc(4096L * 1024 * 2);
  u16* kb  = (u16*)alloc(4096L * 1024 * 2);
  u16* vb  = (u16*)alloc(4096L * 1024 * 2);
  u16* wtq = (u16*)alloc(1024L * 1024 * 2);
  u16* wtk = (u16*)alloc(1024L * 1024 * 2);
  u16* wtv = (u16*)alloc(1024L * 1024 * 2);
  u16* wto = (u16*)alloc(1024L * 1024 * 2);
  u16* Qp  = (u16*)alloc(4096L * 1024 * 2);
  u16* Kp  = (u16*)alloc(4096L * 1024 * 2);
  u16* Vtb = (u16*)alloc(4096L * 1024 * 2);
  u16* ctx = qb;  // reuse: query-bf16 dead after Q projection
  (void)kb; (void)vb; (void)wtk; (void)wtv; (void)Kp;

  // fused pre-pass: input casts + all weight transposes in one launch
  k_prep<<<13312, 256, 0, stream>>>(Ptr3{query, key, value}, qb,
                                    Ptr3{Wq, Wk, Wv}, out_w, wtq, wto);

  // fused Q,K,V projections; z==2 writes Vt[bh][d][l] directly
  k_gemm_qkv<<<dim3(8, 32, 3), 256, 0, stream>>>(qb, wtq, Qp, Vtb, QSCALE);

  // attention: grid 256 = 8 q-tiles x 32 bh, bh in low 5 bits for XCD affinity
  k_flash<<<256, 512, 0, stream>>>(Qp, Kp, Vtb, ctx);

  // output projection + bias -> f32 (128x128, BK=64)
  k_gemm_out<<<dim3(8, 32), 256, 0, stream>>>(ctx, wto, out, out_b);
}

// Round 5
// 233.164 us; speedup vs baseline: 1.0080x; 1.0080x over previous
//
#include <hip/hip_runtime.h>
#include <cstdint>

typedef uint16_t u16;
typedef __attribute__((ext_vector_type(8))) short bf16x8;
typedef __attribute__((ext_vector_type(4))) short bf16x4;
typedef __attribute__((ext_vector_type(4))) float f32x4;

// 0.125 * log2(e): folded into Q projection so softmax is exp2(s) directly.
#define QSCALE 0.18033688011112042f

struct Ptr3 { const float* a; const float* b; const float* c; };

__device__ __forceinline__ u16 f2bf(float x) {
  union { float f; uint32_t u; } v; v.f = x;
  uint32_t r = (v.u + 0x7fffu + ((v.u >> 16) & 1u)) >> 16;
  return (u16)r;
}

// packed f32x2 -> bf16x2 (low = a, high = b). gfx950 has a HW instruction.
#if __has_builtin(__builtin_amdgcn_cvt_pk_bf16_f32)
typedef __bf16 bf2_t __attribute__((ext_vector_type(2)));
__device__ __forceinline__ uint32_t pkbf(float a, float b) {
  bf2_t v = __builtin_amdgcn_cvt_pk_bf16_f32(a, b);
  uint32_t u;
  __builtin_memcpy(&u, &v, 4);
  return u;
}
#else
__device__ __forceinline__ uint32_t pkbf(float a, float b) {
  return (uint32_t)f2bf(a) | ((uint32_t)f2bf(b) << 16);
}
#endif

// async global->LDS, 16B per lane. LDS dest is wave-uniform base + lane*16.
__device__ __forceinline__ void async16(void* lds, const void* g) {
  __builtin_amdgcn_global_load_lds((const __attribute__((address_space(1))) void*)g,
                                   (__attribute__((address_space(3))) void*)lds, 16, 0, 0);
}

// -------- fused pre-pass: input casts (12288 blocks) + weight transposes ---
// bx<12288: f32->bf16 cast of q/k/v. bx>=12288: 1024 transpose blocks
// (768 for Wq/Wk/Wv -> wt[w][h*64+k][d], 256 for out_w (KxN) -> wto (NxK)).
__global__ __launch_bounds__(256) void k_prep(Ptr3 in, u16* __restrict__ out,
                                              Ptr3 w, const float* __restrict__ ow,
                                              u16* __restrict__ wt, u16* __restrict__ wto) {
  __shared__ u16 tile[64 * 65];
  const int t = threadIdx.x;
  const int bx = blockIdx.x;
  if (bx < 12288) {
    int z = bx >> 12;
    int i = (bx & 4095) * 256 + t;
    const float* p = z == 0 ? in.a : (z == 1 ? in.b : in.c);
    float4 v = ((const float4*)p)[i];
    uint2 o2;
    o2.x = pkbf(v.x, v.y);
    o2.y = pkbf(v.z, v.w);
    *(uint2*)(out + (long)z * 4194304 + (long)i * 4) = o2;
    return;
  }
  const int b2 = bx - 12288;
  const float* src;
  long in_base, out_base;
  int rstr, r0, c0;
  u16* outp;
  if (b2 < 768) {
    int z = b2 >> 4;
    r0 = (b2 & 15) * 64; c0 = 0;
    src = (z < 16) ? w.a : (z < 32 ? w.b : w.c);
    in_base = (long)(z & 15) * 65536;
    out_base = (long)z * 65536;
    rstr = 64; outp = wt;
  } else {
    int idx = b2 - 768;
    r0 = (idx >> 4) * 64; c0 = (idx & 15) * 64;
    src = ow; in_base = 0; out_base = 0;
    rstr = 1024; outp = wto;
  }
  for (int e = t; e < 4096; e += 256) {
    int rr = e >> 6, cc = e & 63;
    tile[rr * 65 + cc] = f2bf(src[in_base + (long)(r0 + rr) * rstr + c0 + cc]);
  }
  __syncthreads();
  for (int s = t; s < 512; s += 256) {
    int cc = s >> 3, r8 = (s & 7) << 3;
    bf16x8 p;
    #pragma unroll
    for (int j = 0; j < 8; ++j) p[j] = (short)tile[(r8 + j) * 65 + cc];
    *(bf16x8*)(outp + out_base + (long)(c0 + cc) * 1024 + r0 + r8) = p;
  }
}

// ---------------- fused QKV GEMM: 128x128 tile, BK=64, grid (8,32,3) -------
// (R2-verbatim)
__global__ __launch_bounds__(256) void k_gemm_qkv(const u16* __restrict__ A0,
                                                  const u16* __restrict__ B0,
                                                  u16* __restrict__ C0,
                                                  u16* __restrict__ Vt, float scale0) {
  __shared__ __align__(16) u16 smem[16640];   // As[0:8192) Bs[8192:16384) T[0:16640)
  u16* As = smem;
  u16* Bs = smem + 8192;
  u16* T  = smem;                             // z==2 epilogue only (128 x 130)
  const int z = blockIdx.z;
  const u16* A = A0 + (long)z * 4194304;
  const u16* Bt = B0 + (long)z * 1048576;
  const int t = threadIdx.x, lane = t & 63, quad = lane >> 4, l16 = lane & 15;
  const int wave = t >> 6, wy = wave >> 1, wx = wave & 1;
  const int m0 = blockIdx.y * 128, n0 = blockIdx.x * 128;
  const int wbase = t & 192;
  f32x4 acc[4][4] = {};
  for (int k0 = 0; k0 < 1024; k0 += 64) {
    __syncthreads();
    #pragma unroll
    for (int i = 0; i < 4; ++i) {
      int sb = i * 256 + wbase;
      int s = sb + lane;
      int row = s >> 3, c = s & 7;
      int cs = c ^ (row & 7);              // source chunk for LDS pos c
      async16(As + sb * 8, A + (long)(m0 + row) * 1024 + k0 + cs * 8);
      async16(Bs + sb * 8, Bt + (long)(n0 + row) * 1024 + k0 + cs * 8);
    }
    __syncthreads();
    #pragma unroll
    for (int kk = 0; kk < 2; ++kk) {
      bf16x8 af[4], bfr[4];
      #pragma unroll
      for (int mt = 0; mt < 4; ++mt) {
        int row = wy * 64 + mt * 16 + l16;
        int pos = (kk * 4 + quad) ^ (row & 7);
        af[mt] = *(const bf16x8*)(As + row * 64 + pos * 8);
      }
      #pragma unroll
      for (int nt = 0; nt < 4; ++nt) {
        int row = wx * 64 + nt * 16 + l16;
        int pos = (kk * 4 + quad) ^ (row & 7);
        bfr[nt] = *(const bf16x8*)(Bs + row * 64 + pos * 8);
      }
      #pragma unroll
      for (int mt = 0; mt < 4; ++mt)
        #pragma unroll
        for (int nt = 0; nt < 4; ++nt)
          acc[mt][nt] = __builtin_amdgcn_mfma_f32_16x16x32_bf16(af[mt], bfr[nt], acc[mt][nt], 0, 0, 0);
    }
  }
  if (z < 2) {
    u16* C = C0 + (long)z * 4194304;
    const float scale = z ? 1.0f : scale0;
    #pragma unroll
    for (int mt = 0; mt < 4; ++mt)
      #pragma unroll
      for (int nt = 0; nt < 4; ++nt) {
        int col = n0 + wx * 64 + nt * 16 + l16;
        int row = m0 + wy * 64 + mt * 16 + quad * 4;
        uint32_t ua = pkbf(acc[mt][nt][0] * scale, acc[mt][nt][1] * scale);
        uint32_t ub = pkbf(acc[mt][nt][2] * scale, acc[mt][nt][3] * scale);
        C[(long)row * 1024 + col] = (u16)ua;
        C[(long)(row + 1) * 1024 + col] = (u16)(ua >> 16);
        C[(long)(row + 2) * 1024 + col] = (u16)ub;
        C[(long)(row + 3) * 1024 + col] = (u16)(ub >> 16);
      }
  } else {
    __syncthreads();  // all waves done reading As/Bs before T overlays them
    #pragma unroll
    for (int mt = 0; mt < 4; ++mt)
      #pragma unroll
      for (int nt = 0; nt < 4; ++nt) {
        int cc = wx * 64 + nt * 16 + l16;
        int rr = wy * 64 + mt * 16 + quad * 4;
        uint32_t ua = pkbf(acc[mt][nt][0], acc[mt][nt][1]);
        uint32_t ub = pkbf(acc[mt][nt][2], acc[mt][nt][3]);
        T[(rr + 0) * 130 + cc] = (u16)ua;
        T[(rr + 1) * 130 + cc] = (u16)(ua >> 16);
        T[(rr + 2) * 130 + cc] = (u16)ub;
        T[(rr + 3) * 130 + cc] = (u16)(ub >> 16);
      }
    __syncthreads();
    const int h0 = blockIdx.x * 2, bb = m0 >> 11, lb = m0 & 2047;
    #pragma unroll
    for (int i = 0; i < 8; ++i) {
      int s = t + i * 256;           // 0..2047 = 128 cols x 16 l-chunks
      int c = s >> 4, l0 = (s & 15) * 8;
      bf16x8 p;
      #pragma unroll
      for (int j = 0; j < 8; ++j) p[j] = (short)T[(l0 + j) * 130 + c];
      *(bf16x8*)(Vt + (long)(bb * 16 + h0 + (c >> 6)) * 131072 +
                 (long)(c & 63) * 2048 + lb + l0) = p;
    }
  }
}

// ---- out-proj GEMM: 128x64 tile, grid (16,32), async16, f32 out + bias ----
// (R2-verbatim; the 128x128/BK=64 port in R4 was neutral -> reverted)
__global__ __launch_bounds__(256) void k_gemm_out(const u16* __restrict__ A,
                                                  const u16* __restrict__ Bt,
                                                  float* __restrict__ C,
                                                  const float* __restrict__ bias) {
  __shared__ __align__(16) u16 As[128 * 32];
  __shared__ __align__(16) u16 Bs[64 * 32];
  const int t = threadIdx.x, lane = t & 63, quad = lane >> 4, l16 = lane & 15;
  const int wave = t >> 6;
  const int m0 = blockIdx.y * 128, n0 = blockIdx.x * 64;
  const int wbase = t & 192;
  f32x4 acc[2][4] = {};
  for (int k0 = 0; k0 < 1024; k0 += 32) {
    __syncthreads();
    #pragma unroll
    for (int i = 0; i < 2; ++i) {
      int sb = i * 256 + wbase;
      int s = sb + lane;
      int row = s >> 2, c = s & 3;
      async16(As + sb * 8, A + (long)(m0 + row) * 1024 + k0 + c * 8);
    }
    {
      int s = t;
      int row = s >> 2, c = s & 3;
      async16(Bs + wbase * 8, Bt + (long)(n0 + row) * 1024 + k0 + c * 8);
    }
    __syncthreads();
    bf16x8 af[2], bfr[4];
    #pragma unroll
    for (int mt = 0; mt < 2; ++mt)
      af[mt] = *(const bf16x8*)(As + (wave * 32 + mt * 16 + l16) * 32 + quad * 8);
    #pragma unroll
    for (int nt = 0; nt < 4; ++nt)
      bfr[nt] = *(const bf16x8*)(Bs + (nt * 16 + l16) * 32 + quad * 8);
    #pragma unroll
    for (int mt = 0; mt < 2; ++mt)
      #pragma unroll
      for (int nt = 0; nt < 4; ++nt)
        acc[mt][nt] = __builtin_amdgcn_mfma_f32_16x16x32_bf16(af[mt], bfr[nt], acc[mt][nt], 0, 0, 0);
  }
  #pragma unroll
  for (int mt = 0; mt < 2; ++mt)
    #pragma unroll
    for (int nt = 0; nt < 4; ++nt) {
      int col = n0 + nt * 16 + l16;
      #pragma unroll
      for (int r = 0; r < 4; ++r) {
        int row = m0 + wave * 32 + mt * 16 + quad * 4 + r;
        C[(long)row * 1024 + col] = acc[mt][nt][r] + bias[col];
      }
    }
}

// ---------------- flash attention (R2 structure + swizzled P buffer) -------
// 512 threads, q-tile 256, grid 256 = 1 block/CU. R2's proven 57.4us body;
// R4 proved barrier count is NOT the stall (halving it was +2us). R2 PMC
// accounting: LDS pipe ~75% busy incl. ~900 conflict-cyc/kt/CU, dominated by
// the P-store 2-way alias (bank = 4*l16+2*quad: l16 and l16+8 collide).
// THIS round: 16B-chunk rotation within each P row, C' = (C + 6*l16) & 7.
// bank-group = (l16 + C') mod 8 = (C - l16) mod 8 -> bijection in l16 =>
// b64 stores uniform 4/bank (minimum) and b128 reads uniform 8/bank
// (minimum): both conflict-free. 16B alignment kept; all addrs loop-inv.
__global__ __launch_bounds__(512, 2) void k_flash(const u16* __restrict__ Qp,
                                                  const u16* __restrict__ Kp,
                                                  const u16* __restrict__ Vt,
                                                  u16* __restrict__ ctx) {
  __shared__ __align__(16) u16 qs[256 * 64];   // 32KB Q stage; reused as P buffers
  __shared__ __align__(16) u16 ks[64 * 72];    // K tile, padded rows
  __shared__ __align__(16) u16 vs[64 * 72];    // V^T tile, padded rows
  const int t = threadIdx.x, lane = t & 63, quad = lane >> 4, l16 = lane & 15;
  const int wave = t >> 6;                      // 0..7
  const int bh = blockIdx.x & 31, b = bh >> 4, h = bh & 15;
  const int q0 = (blockIdx.x >> 5) * 256;
  const long gkbase = (long)b * 2097152 + h * 64;
  const long gvbase = (long)bh * 131072;
  const int srow = t >> 3, sc = t & 7;          // staging: row 0..63, 16B chunk 0..7

  // ---- startup: Q via async16 (XOR swizzle), K/V tile 0 via regs ----
  {
    long gq = (long)(b * 2048 + q0) * 1024 + h * 64;
    #pragma unroll
    for (int i = 0; i < 4; ++i) {
      int s = i * 512 + t;
      int row = s >> 3, pos = s & 7, c = pos ^ (row & 7);
      async16(qs + (long)s * 8, Qp + gq + (long)row * 1024 + c * 8);
    }
  }
  bf16x8 kreg = *(const bf16x8*)(Kp + gkbase + (long)srow * 1024 + sc * 8);
  bf16x8 vreg = *(const bf16x8*)(Vt + gvbase + (long)srow * 2048 + sc * 8);
  __syncthreads();  // Q visible

  bf16x8 qf[2][2];
  #pragma unroll
  for (int msub = 0; msub < 2; ++msub)
    #pragma unroll
    for (int kh = 0; kh < 2; ++kh) {
      int m = wave * 32 + msub * 16 + l16;
      int pos = (kh * 4 + quad) ^ (m & 7);
      qf[msub][kh] = *(const bf16x8*)(qs + m * 64 + pos * 8);
    }
  *(bf16x8*)(ks + srow * 72 + sc * 8) = kreg;
  *(bf16x8*)(vs + srow * 72 + sc * 8) = vreg;
  __syncthreads();  // K/V tile 0 visible; all qf reads drained -> qs safe as P

  u16* pw = qs + wave * 1152;  // per-wave P tile: 16 q-rows x 72 (one msub at a time)

  float ls[2] = {};
  f32x4 o[2][4] = {};

  for (int kt = 0; kt < 32; ++kt) {
    // register prefetch of next K/V tile (in flight across this compute phase)
    if (kt < 31) {
      int kv0 = (kt + 1) * 64;
      kreg = *(const bf16x8*)(Kp + gkbase + (long)(kv0 + srow) * 1024 + sc * 8);
      vreg = *(const bf16x8*)(Vt + gvbase + kv0 + (long)srow * 2048 + sc * 8);
    }

    // K and V^T fragments (vector b128, <=2-way banks)
    bf16x8 kf[4][2], vf[4][2];
    #pragma unroll
    for (int nt = 0; nt < 4; ++nt)
      #pragma unroll
      for (int kh = 0; kh < 2; ++kh) {
        kf[nt][kh] = *(const bf16x8*)(ks + (nt * 16 + l16) * 72 + kh * 32 + quad * 8);
        vf[nt][kh] = *(const bf16x8*)(vs + (nt * 16 + l16) * 72 + kh * 32 + quad * 8);
      }

    #pragma unroll
    for (int msub = 0; msub < 2; ++msub) {
      // S^T(64x16) = K @ Q^T ; lane holds S[q=l16][kv=nt*16+quad*4+r].
      // p = exp2(s); one b64 store per nt, chunk-rotated -> conflict-free.
      #pragma unroll
      for (int nt = 0; nt < 4; ++nt) {
        f32x4 a = {};
        #pragma unroll
        for (int kh = 0; kh < 2; ++kh)
          a = __builtin_amdgcn_mfma_f32_16x16x32_bf16(kf[nt][kh], qf[msub][kh], a, 0, 0, 0);
        float e0 = __builtin_amdgcn_exp2f(a[0]);
        float e1 = __builtin_amdgcn_exp2f(a[1]);
        float e2 = __builtin_amdgcn_exp2f(a[2]);
        float e3 = __builtin_amdgcn_exp2f(a[3]);
        ls[msub] += (e0 + e1) + (e2 + e3);
        uint2 w;
        w.x = pkbf(e0, e1);
        w.y = pkbf(e2, e3);
        int cs = ((nt * 2 + (quad >> 1)) + 6 * l16) & 7;   // rotated 16B chunk
        *(uint2*)(pw + l16 * 72 + cs * 8 + (quad & 1) * 4) = w;
      }
      // O(16x64) += P @ V : A-frag = b128 at the same rotated chunk index
      #pragma unroll
      for (int kh = 0; kh < 2; ++kh) {
        int cr = ((kh * 4 + quad) + 6 * l16) & 7;          // rotated 16B chunk
        bf16x8 pa = *(const bf16x8*)(pw + l16 * 72 + cr * 8);
        #pragma unroll
        for (int nt = 0; nt < 4; ++nt)
          o[msub][nt] = __builtin_amdgcn_mfma_f32_16x16x32_bf16(pa, vf[nt][kh], o[msub][nt], 0, 0, 0);
      }
    }

    __syncthreads();  // all waves done reading ks/vs (and prefetch drained)
    if (kt < 31) {
      *(bf16x8*)(ks + srow * 72 + sc * 8) = kreg;
      *(bf16x8*)(vs + srow * 72 + sc * 8) = vreg;
    }
    __syncthreads();  // next tile visible
  }

  // final l: reduce over the 4 quads (each lane holds partial for q=l16),
  // reciprocal, then shuffle 1/l to the lanes holding output rows quad*4+r.
  #pragma unroll
  for (int msub = 0; msub < 2; ++msub) {
    float l = ls[msub];
    l += __shfl_xor(l, 16);
    l += __shfl_xor(l, 32);
    float linv = 1.0f / l;                 // valid for q = l16 on every lane
    float li0 = __shfl(linv, quad * 4 + 0);
    float li1 = __shfl(linv, quad * 4 + 1);
    float li2 = __shfl(linv, quad * 4 + 2);
    float li3 = __shfl(linv, quad * 4 + 3);
    #pragma unroll
    for (int nt = 0; nt < 4; ++nt) {
      int q = q0 + wave * 32 + msub * 16 + quad * 4;
      long idx = (long)(b * 2048 + q) * 1024 + h * 64 + nt * 16 + l16;
      uint32_t ua = pkbf(o[msub][nt][0] * li0, o[msub][nt][1] * li1);
      uint32_t ub = pkbf(o[msub][nt][2] * li2, o[msub][nt][3] * li3);
      ctx[idx]        = (u16)ua;
      ctx[idx + 1024] = (u16)(ua >> 16);
      ctx[idx + 2048] = (u16)ub;
      ctx[idx + 3072] = (u16)(ub >> 16);
    }
  }
}

extern "C" void kernel_launch(void* const* d_in, const int* in_sizes, int n_in,
                              void* d_out, int out_size, void* d_ws, size_t ws_size,
                              hipStream_t stream) {
  const float* query = (const float*)d_in[0];
  const float* key   = (const float*)d_in[1];
  const float* value = (const float*)d_in[2];
  const float* Wq    = (const float*)d_in[3];
  const float* Wk    = (const float*)d_in[4];
  const float* Wv    = (const float*)d_in[5];
  const float* out_w = (const float*)d_in[6];
  const float* out_b = (const float*)d_in[7];
  // d_in[8] = coupling: unused — per-head scalar bias is softmax-invariant.
  float* out = (float*)d_out;

  char* ws = (char*)d_ws;
  size_t off = 0;
  auto alloc = [&](size_t bytes) {
    void* p = ws + off;
    off += (bytes + 255) & ~(size_t)255;
    return p;
  };
  // qb,kb,vb contiguous (k_prep cast z-stride); wtq..wtv contiguous
  // (k_prep transpose z-stride); Qp,Kp contiguous (k_gemm_qkv z<2 stride).
  u16* qb  = (u16*)alloc(4096L * 1024 * 2);
  u16* kb  = (u16*)alloc(4096L * 1024 * 2);
  u16* vb  = (u16*)alloc(4096L * 1024 * 2);
  u16* wtq = (u16*)alloc(1024L * 1024 * 2);
  u16* wtk = (u16*)alloc(1024L * 1024 * 2);
  u16* wtv = (u16*)alloc(1024L * 1024 * 2);
  u16* wto = (u16*)alloc(1024L * 1024 * 2);
  u16* Qp  = (u16*)alloc(4096L * 1024 * 2);
  u16* Kp  = (u16*)alloc(4096L * 1024 * 2);
  u16* Vtb = (u16*)alloc(4096L * 1024 * 2);
  u16* ctx = qb;  // reuse: query-bf16 dead after Q projection
  (void)kb; (void)vb; (void)wtk; (void)wtv; (void)Kp;

  // fused pre-pass: input casts + all weight transposes in one launch
  k_prep<<<13312, 256, 0, stream>>>(Ptr3{query, key, value}, qb,
                                    Ptr3{Wq, Wk, Wv}, out_w, wtq, wto);

  // fused Q,K,V projections; z==2 writes Vt[bh][d][l] directly
  k_gemm_qkv<<<dim3(8, 32, 3), 256, 0, stream>>>(qb, wtq, Qp, Vtb, QSCALE);

  // attention: grid 256 = 8 q-tiles x 32 bh, bh in low 5 bits for XCD affinity
  k_flash<<<256, 512, 0, stream>>>(Qp, Kp, Vtb, ctx);

  // output projection + bias -> f32
  k_gemm_out<<<dim3(16, 32), 256, 0, stream>>>(ctx, wto, out, out_b);
}

// Round 6
// 232.813 us; speedup vs baseline: 1.0095x; 1.0015x over previous
//
#include <hip/hip_runtime.h>
#include <cstdint>

typedef uint16_t u16;
typedef __attribute__((ext_vector_type(8))) short bf16x8;
typedef __attribute__((ext_vector_type(4))) short bf16x4;
typedef __attribute__((ext_vector_type(4))) float f32x4;

// 0.125 * log2(e): folded into Q projection so softmax is exp2(s) directly.
#define QSCALE 0.18033688011112042f

struct Ptr3 { const float* a; const float* b; const float* c; };

__device__ __forceinline__ u16 f2bf(float x) {
  union { float f; uint32_t u; } v; v.f = x;
  uint32_t r = (v.u + 0x7fffu + ((v.u >> 16) & 1u)) >> 16;
  return (u16)r;
}

// packed f32x2 -> bf16x2 (low = a, high = b). gfx950 has a HW instruction.
#if __has_builtin(__builtin_amdgcn_cvt_pk_bf16_f32)
typedef __bf16 bf2_t __attribute__((ext_vector_type(2)));
__device__ __forceinline__ uint32_t pkbf(float a, float b) {
  bf2_t v = __builtin_amdgcn_cvt_pk_bf16_f32(a, b);
  uint32_t u;
  __builtin_memcpy(&u, &v, 4);
  return u;
}
#else
__device__ __forceinline__ uint32_t pkbf(float a, float b) {
  return (uint32_t)f2bf(a) | ((uint32_t)f2bf(b) << 16);
}
#endif

// async global->LDS, 16B per lane. LDS dest is wave-uniform base + lane*16.
__device__ __forceinline__ void async16(void* lds, const void* g) {
  __builtin_amdgcn_global_load_lds((const __attribute__((address_space(1))) void*)g,
                                   (__attribute__((address_space(3))) void*)lds, 16, 0, 0);
}

// -------- fused pre-pass: input casts (12288 blocks) + weight transposes ---
// bx<12288: f32->bf16 cast of q/k/v. bx>=12288: 1024 transpose blocks
// (768 for Wq/Wk/Wv -> wt[w][h*64+k][d], 256 for out_w (KxN) -> wto (NxK)).
__global__ __launch_bounds__(256) void k_prep(Ptr3 in, u16* __restrict__ out,
                                              Ptr3 w, const float* __restrict__ ow,
                                              u16* __restrict__ wt, u16* __restrict__ wto) {
  __shared__ u16 tile[64 * 65];
  const int t = threadIdx.x;
  const int bx = blockIdx.x;
  if (bx < 12288) {
    int z = bx >> 12;
    int i = (bx & 4095) * 256 + t;
    const float* p = z == 0 ? in.a : (z == 1 ? in.b : in.c);
    float4 v = ((const float4*)p)[i];
    uint2 o2;
    o2.x = pkbf(v.x, v.y);
    o2.y = pkbf(v.z, v.w);
    *(uint2*)(out + (long)z * 4194304 + (long)i * 4) = o2;
    return;
  }
  const int b2 = bx - 12288;
  const float* src;
  long in_base, out_base;
  int rstr, r0, c0;
  u16* outp;
  if (b2 < 768) {
    int z = b2 >> 4;
    r0 = (b2 & 15) * 64; c0 = 0;
    src = (z < 16) ? w.a : (z < 32 ? w.b : w.c);
    in_base = (long)(z & 15) * 65536;
    out_base = (long)z * 65536;
    rstr = 64; outp = wt;
  } else {
    int idx = b2 - 768;
    r0 = (idx >> 4) * 64; c0 = (idx & 15) * 64;
    src = ow; in_base = 0; out_base = 0;
    rstr = 1024; outp = wto;
  }
  for (int e = t; e < 4096; e += 256) {
    int rr = e >> 6, cc = e & 63;
    tile[rr * 65 + cc] = f2bf(src[in_base + (long)(r0 + rr) * rstr + c0 + cc]);
  }
  __syncthreads();
  for (int s = t; s < 512; s += 256) {
    int cc = s >> 3, r8 = (s & 7) << 3;
    bf16x8 p;
    #pragma unroll
    for (int j = 0; j < 8; ++j) p[j] = (short)tile[(r8 + j) * 65 + cc];
    *(bf16x8*)(outp + out_base + (long)(c0 + cc) * 1024 + r0 + r8) = p;
  }
}

// ---------------- fused QKV GEMM: 128x128 tile, BK=64, grid (8,32,3) -------
// (R2-verbatim)
__global__ __launch_bounds__(256) void k_gemm_qkv(const u16* __restrict__ A0,
                                                  const u16* __restrict__ B0,
                                                  u16* __restrict__ C0,
                                                  u16* __restrict__ Vt, float scale0) {
  __shared__ __align__(16) u16 smem[16640];   // As[0:8192) Bs[8192:16384) T[0:16640)
  u16* As = smem;
  u16* Bs = smem + 8192;
  u16* T  = smem;                             // z==2 epilogue only (128 x 130)
  const int z = blockIdx.z;
  const u16* A = A0 + (long)z * 4194304;
  const u16* Bt = B0 + (long)z * 1048576;
  const int t = threadIdx.x, lane = t & 63, quad = lane >> 4, l16 = lane & 15;
  const int wave = t >> 6, wy = wave >> 1, wx = wave & 1;
  const int m0 = blockIdx.y * 128, n0 = blockIdx.x * 128;
  const int wbase = t & 192;
  f32x4 acc[4][4] = {};
  for (int k0 = 0; k0 < 1024; k0 += 64) {
    __syncthreads();
    #pragma unroll
    for (int i = 0; i < 4; ++i) {
      int sb = i * 256 + wbase;
      int s = sb + lane;
      int row = s >> 3, c = s & 7;
      int cs = c ^ (row & 7);              // source chunk for LDS pos c
      async16(As + sb * 8, A + (long)(m0 + row) * 1024 + k0 + cs * 8);
      async16(Bs + sb * 8, Bt + (long)(n0 + row) * 1024 + k0 + cs * 8);
    }
    __syncthreads();
    #pragma unroll
    for (int kk = 0; kk < 2; ++kk) {
      bf16x8 af[4], bfr[4];
      #pragma unroll
      for (int mt = 0; mt < 4; ++mt) {
        int row = wy * 64 + mt * 16 + l16;
        int pos = (kk * 4 + quad) ^ (row & 7);
        af[mt] = *(const bf16x8*)(As + row * 64 + pos * 8);
      }
      #pragma unroll
      for (int nt = 0; nt < 4; ++nt) {
        int row = wx * 64 + nt * 16 + l16;
        int pos = (kk * 4 + quad) ^ (row & 7);
        bfr[nt] = *(const bf16x8*)(Bs + row * 64 + pos * 8);
      }
      #pragma unroll
      for (int mt = 0; mt < 4; ++mt)
        #pragma unroll
        for (int nt = 0; nt < 4; ++nt)
          acc[mt][nt] = __builtin_amdgcn_mfma_f32_16x16x32_bf16(af[mt], bfr[nt], acc[mt][nt], 0, 0, 0);
    }
  }
  if (z < 2) {
    u16* C = C0 + (long)z * 4194304;
    const float scale = z ? 1.0f : scale0;
    #pragma unroll
    for (int mt = 0; mt < 4; ++mt)
      #pragma unroll
      for (int nt = 0; nt < 4; ++nt) {
        int col = n0 + wx * 64 + nt * 16 + l16;
        int row = m0 + wy * 64 + mt * 16 + quad * 4;
        uint32_t ua = pkbf(acc[mt][nt][0] * scale, acc[mt][nt][1] * scale);
        uint32_t ub = pkbf(acc[mt][nt][2] * scale, acc[mt][nt][3] * scale);
        C[(long)row * 1024 + col] = (u16)ua;
        C[(long)(row + 1) * 1024 + col] = (u16)(ua >> 16);
        C[(long)(row + 2) * 1024 + col] = (u16)ub;
        C[(long)(row + 3) * 1024 + col] = (u16)(ub >> 16);
      }
  } else {
    __syncthreads();  // all waves done reading As/Bs before T overlays them
    #pragma unroll
    for (int mt = 0; mt < 4; ++mt)
      #pragma unroll
      for (int nt = 0; nt < 4; ++nt) {
        int cc = wx * 64 + nt * 16 + l16;
        int rr = wy * 64 + mt * 16 + quad * 4;
        uint32_t ua = pkbf(acc[mt][nt][0], acc[mt][nt][1]);
        uint32_t ub = pkbf(acc[mt][nt][2], acc[mt][nt][3]);
        T[(rr + 0) * 130 + cc] = (u16)ua;
        T[(rr + 1) * 130 + cc] = (u16)(ua >> 16);
        T[(rr + 2) * 130 + cc] = (u16)ub;
        T[(rr + 3) * 130 + cc] = (u16)(ub >> 16);
      }
    __syncthreads();
    const int h0 = blockIdx.x * 2, bb = m0 >> 11, lb = m0 & 2047;
    #pragma unroll
    for (int i = 0; i < 8; ++i) {
      int s = t + i * 256;           // 0..2047 = 128 cols x 16 l-chunks
      int c = s >> 4, l0 = (s & 15) * 8;
      bf16x8 p;
      #pragma unroll
      for (int j = 0; j < 8; ++j) p[j] = (short)T[(l0 + j) * 130 + c];
      *(bf16x8*)(Vt + (long)(bb * 16 + h0 + (c >> 6)) * 131072 +
                 (long)(c & 63) * 2048 + lb + l0) = p;
    }
  }
}

// ---- out-proj GEMM: 128x64 tile, grid (16,32), async16, f32 out + bias ----
// (R2-verbatim)
__global__ __launch_bounds__(256) void k_gemm_out(const u16* __restrict__ A,
                                                  const u16* __restrict__ Bt,
                                                  float* __restrict__ C,
                                                  const float* __restrict__ bias) {
  __shared__ __align__(16) u16 As[128 * 32];
  __shared__ __align__(16) u16 Bs[64 * 32];
  const int t = threadIdx.x, lane = t & 63, quad = lane >> 4, l16 = lane & 15;
  const int wave = t >> 6;
  const int m0 = blockIdx.y * 128, n0 = blockIdx.x * 64;
  const int wbase = t & 192;
  f32x4 acc[2][4] = {};
  for (int k0 = 0; k0 < 1024; k0 += 32) {
    __syncthreads();
    #pragma unroll
    for (int i = 0; i < 2; ++i) {
      int sb = i * 256 + wbase;
      int s = sb + lane;
      int row = s >> 2, c = s & 3;
      async16(As + sb * 8, A + (long)(m0 + row) * 1024 + k0 + c * 8);
    }
    {
      int s = t;
      int row = s >> 2, c = s & 3;
      async16(Bs + wbase * 8, Bt + (long)(n0 + row) * 1024 + k0 + c * 8);
    }
    __syncthreads();
    bf16x8 af[2], bfr[4];
    #pragma unroll
    for (int mt = 0; mt < 2; ++mt)
      af[mt] = *(const bf16x8*)(As + (wave * 32 + mt * 16 + l16) * 32 + quad * 8);
    #pragma unroll
    for (int nt = 0; nt < 4; ++nt)
      bfr[nt] = *(const bf16x8*)(Bs + (nt * 16 + l16) * 32 + quad * 8);
    #pragma unroll
    for (int mt = 0; mt < 2; ++mt)
      #pragma unroll
      for (int nt = 0; nt < 4; ++nt)
        acc[mt][nt] = __builtin_amdgcn_mfma_f32_16x16x32_bf16(af[mt], bfr[nt], acc[mt][nt], 0, 0, 0);
  }
  #pragma unroll
  for (int mt = 0; mt < 2; ++mt)
    #pragma unroll
    for (int nt = 0; nt < 4; ++nt) {
      int col = n0 + nt * 16 + l16;
      #pragma unroll
      for (int r = 0; r < 4; ++r) {
        int row = m0 + wave * 32 + mt * 16 + quad * 4 + r;
        C[(long)row * 1024 + col] = acc[mt][nt][r] + bias[col];
      }
    }
}

// ------ flash attention (R2 per-wave body, 4-wave blocks, 2 blocks/CU) -----
// THE ONLY change vs the proven R2 57.4us kernel: block = 4 waves / q-tile
// 128 (each wave still owns 32 q-rows -> per-wave MFMA:LDS ratio IDENTICAL
// to R2; R1's regression came from halving per-wave q, not co-residency).
// Grid 512 = 16 q-tiles x 32 bh -> 2 blocks/CU. Barriers now drain 4 waves,
// and the two co-resident blocks' barrier phases are unsynchronized, so one
// block's compute covers the other's stage/drain. LDS 34KB/block (68KB/CU).
// Same-bh blocks all land on one XCD (bh mod 8): 4 bh x 512KB = 2MB < L2.
// Staging: 256 threads stage 2 K-rows + 2 V-rows each.
__global__ __launch_bounds__(256, 2) void k_flash(const u16* __restrict__ Qp,
                                                  const u16* __restrict__ Kp,
                                                  const u16* __restrict__ Vt,
                                                  u16* __restrict__ ctx) {
  __shared__ __align__(16) u16 qs[128 * 64];   // 16KB Q stage; reused as P buffers
  __shared__ __align__(16) u16 ks[64 * 72];    // K tile, padded rows
  __shared__ __align__(16) u16 vs[64 * 72];    // V^T tile, padded rows
  const int t = threadIdx.x, lane = t & 63, quad = lane >> 4, l16 = lane & 15;
  const int wave = t >> 6;                      // 0..3
  const int bh = blockIdx.x & 31, b = bh >> 4, h = bh & 15;
  const int q0 = (blockIdx.x >> 5) * 128;       // 16 q-tiles
  const long gkbase = (long)b * 2097152 + h * 64;
  const long gvbase = (long)bh * 131072;
  const int srow = t >> 3, sc = t & 7;          // staging: rows srow, srow+32

  // ---- startup: Q via async16 (XOR swizzle), K/V tile 0 via regs ----
  {
    long gq = (long)(b * 2048 + q0) * 1024 + h * 64;
    #pragma unroll
    for (int i = 0; i < 4; ++i) {
      int s = i * 256 + t;
      int row = s >> 3, pos = s & 7, c = pos ^ (row & 7);
      async16(qs + (long)s * 8, Qp + gq + (long)row * 1024 + c * 8);
    }
  }
  bf16x8 kreg0 = *(const bf16x8*)(Kp + gkbase + (long)srow * 1024 + sc * 8);
  bf16x8 kreg1 = *(const bf16x8*)(Kp + gkbase + (long)(srow + 32) * 1024 + sc * 8);
  bf16x8 vreg0 = *(const bf16x8*)(Vt + gvbase + (long)srow * 2048 + sc * 8);
  bf16x8 vreg1 = *(const bf16x8*)(Vt + gvbase + (long)(srow + 32) * 2048 + sc * 8);
  __syncthreads();  // Q visible

  bf16x8 qf[2][2];
  #pragma unroll
  for (int msub = 0; msub < 2; ++msub)
    #pragma unroll
    for (int kh = 0; kh < 2; ++kh) {
      int m = wave * 32 + msub * 16 + l16;
      int pos = (kh * 4 + quad) ^ (m & 7);
      qf[msub][kh] = *(const bf16x8*)(qs + m * 64 + pos * 8);
    }
  *(bf16x8*)(ks + srow * 72 + sc * 8) = kreg0;
  *(bf16x8*)(ks + (srow + 32) * 72 + sc * 8) = kreg1;
  *(bf16x8*)(vs + srow * 72 + sc * 8) = vreg0;
  *(bf16x8*)(vs + (srow + 32) * 72 + sc * 8) = vreg1;
  __syncthreads();  // K/V tile 0 visible; all qf reads drained -> qs safe as P

  u16* pw = qs + wave * 1152;  // per-wave P tile: 16 q-rows x 72 (one msub at a time)

  float ls[2] = {};
  f32x4 o[2][4] = {};

  for (int kt = 0; kt < 32; ++kt) {
    // register prefetch of next K/V tile (in flight across this compute phase)
    if (kt < 31) {
      int kv0 = (kt + 1) * 64;
      kreg0 = *(const bf16x8*)(Kp + gkbase + (long)(kv0 + srow) * 1024 + sc * 8);
      kreg1 = *(const bf16x8*)(Kp + gkbase + (long)(kv0 + srow + 32) * 1024 + sc * 8);
      vreg0 = *(const bf16x8*)(Vt + gvbase + kv0 + (long)srow * 2048 + sc * 8);
      vreg1 = *(const bf16x8*)(Vt + gvbase + kv0 + (long)(srow + 32) * 2048 + sc * 8);
    }

    // K and V^T fragments (vector b128, <=2-way banks)
    bf16x8 kf[4][2], vf[4][2];
    #pragma unroll
    for (int nt = 0; nt < 4; ++nt)
      #pragma unroll
      for (int kh = 0; kh < 2; ++kh) {
        kf[nt][kh] = *(const bf16x8*)(ks + (nt * 16 + l16) * 72 + kh * 32 + quad * 8);
        vf[nt][kh] = *(const bf16x8*)(vs + (nt * 16 + l16) * 72 + kh * 32 + quad * 8);
      }

    #pragma unroll
    for (int msub = 0; msub < 2; ++msub) {
      // S^T(64x16) = K @ Q^T ; lane holds S[q=l16][kv=nt*16+quad*4+r].
      // p = exp2(s); one b64 store per nt -> P[q][kv] row-major in LDS.
      #pragma unroll
      for (int nt = 0; nt < 4; ++nt) {
        f32x4 a = {};
        #pragma unroll
        for (int kh = 0; kh < 2; ++kh)
          a = __builtin_amdgcn_mfma_f32_16x16x32_bf16(kf[nt][kh], qf[msub][kh], a, 0, 0, 0);
        float e0 = __builtin_amdgcn_exp2f(a[0]);
        float e1 = __builtin_amdgcn_exp2f(a[1]);
        float e2 = __builtin_amdgcn_exp2f(a[2]);
        float e3 = __builtin_amdgcn_exp2f(a[3]);
        ls[msub] += (e0 + e1) + (e2 + e3);
        uint2 w;
        w.x = pkbf(e0, e1);
        w.y = pkbf(e2, e3);
        *(uint2*)(pw + l16 * 72 + nt * 16 + quad * 4) = w;
      }
      // O(16x64) += P @ V : A-frag = contiguous b128 rows of P (unchanged)
      #pragma unroll
      for (int kh = 0; kh < 2; ++kh) {
        bf16x8 pa = *(const bf16x8*)(pw + l16 * 72 + kh * 32 + quad * 8);
        #pragma unroll
        for (int nt = 0; nt < 4; ++nt)
          o[msub][nt] = __builtin_amdgcn_mfma_f32_16x16x32_bf16(pa, vf[nt][kh], o[msub][nt], 0, 0, 0);
      }
    }

    __syncthreads();  // all waves done reading ks/vs (and prefetch drained)
    if (kt < 31) {
      *(bf16x8*)(ks + srow * 72 + sc * 8) = kreg0;
      *(bf16x8*)(ks + (srow + 32) * 72 + sc * 8) = kreg1;
      *(bf16x8*)(vs + srow * 72 + sc * 8) = vreg0;
      *(bf16x8*)(vs + (srow + 32) * 72 + sc * 8) = vreg1;
    }
    __syncthreads();  // next tile visible
  }

  // final l: reduce over the 4 quads (each lane holds partial for q=l16),
  // reciprocal, then shuffle 1/l to the lanes holding output rows quad*4+r.
  #pragma unroll
  for (int msub = 0; msub < 2; ++msub) {
    float l = ls[msub];
    l += __shfl_xor(l, 16);
    l += __shfl_xor(l, 32);
    float linv = 1.0f / l;                 // valid for q = l16 on every lane
    float li0 = __shfl(linv, quad * 4 + 0);
    float li1 = __shfl(linv, quad * 4 + 1);
    float li2 = __shfl(linv, quad * 4 + 2);
    float li3 = __shfl(linv, quad * 4 + 3);
    #pragma unroll
    for (int nt = 0; nt < 4; ++nt) {
      int q = q0 + wave * 32 + msub * 16 + quad * 4;
      long idx = (long)(b * 2048 + q) * 1024 + h * 64 + nt * 16 + l16;
      uint32_t ua = pkbf(o[msub][nt][0] * li0, o[msub][nt][1] * li1);
      uint32_t ub = pkbf(o[msub][nt][2] * li2, o[msub][nt][3] * li3);
      ctx[idx]        = (u16)ua;
      ctx[idx + 1024] = (u16)(ua >> 16);
      ctx[idx + 2048] = (u16)ub;
      ctx[idx + 3072] = (u16)(ub >> 16);
    }
  }
}

extern "C" void kernel_launch(void* const* d_in, const int* in_sizes, int n_in,
                              void* d_out, int out_size, void* d_ws, size_t ws_size,
                              hipStream_t stream) {
  const float* query = (const float*)d_in[0];
  const float* key   = (const float*)d_in[1];
  const float* value = (const float*)d_in[2];
  const float* Wq    = (const float*)d_in[3];
  const float* Wk    = (const float*)d_in[4];
  const float* Wv    = (const float*)d_in[5];
  const float* out_w = (const float*)d_in[6];
  const float* out_b = (const float*)d_in[7];
  // d_in[8] = coupling: unused — per-head scalar bias is softmax-invariant.
  float* out = (float*)d_out;

  char* ws = (char*)d_ws;
  size_t off = 0;
  auto alloc = [&](size_t bytes) {
    void* p = ws + off;
    off += (bytes + 255) & ~(size_t)255;
    return p;
  };
  // qb,kb,vb contiguous (k_prep cast z-stride); wtq..wtv contiguous
  // (k_prep transpose z-stride); Qp,Kp contiguous (k_gemm_qkv z<2 stride).
  u16* qb  = (u16*)alloc(4096L * 1024 * 2);
  u16* kb  = (u16*)alloc(4096L * 1024 * 2);
  u16* vb  = (u16*)alloc(4096L * 1024 * 2);
  u16* wtq = (u16*)alloc(1024L * 1024 * 2);
  u16* wtk = (u16*)alloc(1024L * 1024 * 2);
  u16* wtv = (u16*)alloc(1024L * 1024 * 2);
  u16* wto = (u16*)alloc(1024L * 1024 * 2);
  u16* Qp  = (u16*)alloc(4096L * 1024 * 2);
  u16* Kp  = (u16*)alloc(4096L * 1024 * 2);
  u16* Vtb = (u16*)alloc(4096L * 1024 * 2);
  u16* ctx = qb;  // reuse: query-bf16 dead after Q projection
  (void)kb; (void)vb; (void)wtk; (void)wtv; (void)Kp;

  // fused pre-pass: input casts + all weight transposes in one launch
  k_prep<<<13312, 256, 0, stream>>>(Ptr3{query, key, value}, qb,
                                    Ptr3{Wq, Wk, Wv}, out_w, wtq, wto);

  // fused Q,K,V projections; z==2 writes Vt[bh][d][l] directly
  k_gemm_qkv<<<dim3(8, 32, 3), 256, 0, stream>>>(qb, wtq, Qp, Vtb, QSCALE);

  // attention: grid 512 = 16 q-tiles x 32 bh (bh in low 5 bits for XCD
  // affinity), 256 threads, 2 blocks/CU
  k_flash<<<512, 256, 0, stream>>>(Qp, Kp, Vtb, ctx);

  // output projection + bias -> f32
  k_gemm_out<<<dim3(16, 32), 256, 0, stream>>>(ctx, wto, out, out_b);
}

// Round 8
// 223.518 us; speedup vs baseline: 1.0515x; 1.0416x over previous
//
#include <hip/hip_runtime.h>
#include <cstdint>

typedef uint16_t u16;
typedef __attribute__((ext_vector_type(8))) short bf16x8;
typedef __attribute__((ext_vector_type(4))) float f32x4;
typedef __attribute__((ext_vector_type(16))) float f32x16;

// 0.125 * log2(e): folded into Q projection so softmax is exp2(s) directly.
#define QSCALE 0.18033688011112042f

struct Ptr3 { const float* a; const float* b; const float* c; };

__device__ __forceinline__ u16 f2bf(float x) {
  union { float f; uint32_t u; } v; v.f = x;
  uint32_t r = (v.u + 0x7fffu + ((v.u >> 16) & 1u)) >> 16;
  return (u16)r;
}

// packed f32x2 -> bf16x2 (low = a, high = b). gfx950 has a HW instruction.
#if __has_builtin(__builtin_amdgcn_cvt_pk_bf16_f32)
typedef __bf16 bf2_t __attribute__((ext_vector_type(2)));
__device__ __forceinline__ uint32_t pkbf(float a, float b) {
  bf2_t v = __builtin_amdgcn_cvt_pk_bf16_f32(a, b);
  uint32_t u;
  __builtin_memcpy(&u, &v, 4);
  return u;
}
#else
__device__ __forceinline__ uint32_t pkbf(float a, float b) {
  return (uint32_t)f2bf(a) | ((uint32_t)f2bf(b) << 16);
}
#endif

// lane-half swap: a' = {a[0:31], b[0:31]}, b' = {a[32:63], b[32:63]}.
// R7 LESSON: the raw asm form of this produced NaN (compiler can't see the
// cross-lane RMW semantics of a 2x"+v" asm). Use the documented intrinsic
// (guide T12 recipe); shfl fallback keeps it correct if absent.
#if __has_builtin(__builtin_amdgcn_permlane32_swap)
typedef __attribute__((ext_vector_type(2))) int i32x2;
__device__ __forceinline__ void swap32(uint32_t& a, uint32_t& b, int hi) {
  i32x2 r = __builtin_amdgcn_permlane32_swap((int)a, (int)b, false, false);
  a = (uint32_t)r.x;
  b = (uint32_t)r.y;
}
#else
__device__ __forceinline__ void swap32(uint32_t& a, uint32_t& b, int hi) {
  uint32_t ax = (uint32_t)__shfl_xor((int)a, 32);
  uint32_t bx = (uint32_t)__shfl_xor((int)b, 32);
  uint32_t na = hi ? bx : a;   // {a.lo, b.lo}
  uint32_t nb = hi ? b : ax;   // {a.hi, b.hi}
  a = na; b = nb;
}
#endif

// async global->LDS, 16B per lane. LDS dest is wave-uniform base + lane*16.
__device__ __forceinline__ void async16(void* lds, const void* g) {
  __builtin_amdgcn_global_load_lds((const __attribute__((address_space(1))) void*)g,
                                   (__attribute__((address_space(3))) void*)lds, 16, 0, 0);
}

// -------- fused pre-pass: input casts (12288 blocks) + weight transposes ---
// (R2-verbatim)
__global__ __launch_bounds__(256) void k_prep(Ptr3 in, u16* __restrict__ out,
                                              Ptr3 w, const float* __restrict__ ow,
                                              u16* __restrict__ wt, u16* __restrict__ wto) {
  __shared__ u16 tile[64 * 65];
  const int t = threadIdx.x;
  const int bx = blockIdx.x;
  if (bx < 12288) {
    int z = bx >> 12;
    int i = (bx & 4095) * 256 + t;
    const float* p = z == 0 ? in.a : (z == 1 ? in.b : in.c);
    float4 v = ((const float4*)p)[i];
    uint2 o2;
    o2.x = pkbf(v.x, v.y);
    o2.y = pkbf(v.z, v.w);
    *(uint2*)(out + (long)z * 4194304 + (long)i * 4) = o2;
    return;
  }
  const int b2 = bx - 12288;
  const float* src;
  long in_base, out_base;
  int rstr, r0, c0;
  u16* outp;
  if (b2 < 768) {
    int z = b2 >> 4;
    r0 = (b2 & 15) * 64; c0 = 0;
    src = (z < 16) ? w.a : (z < 32 ? w.b : w.c);
    in_base = (long)(z & 15) * 65536;
    out_base = (long)z * 65536;
    rstr = 64; outp = wt;
  } else {
    int idx = b2 - 768;
    r0 = (idx >> 4) * 64; c0 = (idx & 15) * 64;
    src = ow; in_base = 0; out_base = 0;
    rstr = 1024; outp = wto;
  }
  for (int e = t; e < 4096; e += 256) {
    int rr = e >> 6, cc = e & 63;
    tile[rr * 65 + cc] = f2bf(src[in_base + (long)(r0 + rr) * rstr + c0 + cc]);
  }
  __syncthreads();
  for (int s = t; s < 512; s += 256) {
    int cc = s >> 3, r8 = (s & 7) << 3;
    bf16x8 p;
    #pragma unroll
    for (int j = 0; j < 8; ++j) p[j] = (short)tile[(r8 + j) * 65 + cc];
    *(bf16x8*)(outp + out_base + (long)(c0 + cc) * 1024 + r0 + r8) = p;
  }
}

// ---------------- fused QKV GEMM: 128x128 tile, BK=64, grid (8,32,3) -------
// (R2-verbatim)
__global__ __launch_bounds__(256) void k_gemm_qkv(const u16* __restrict__ A0,
                                                  const u16* __restrict__ B0,
                                                  u16* __restrict__ C0,
                                                  u16* __restrict__ Vt, float scale0) {
  __shared__ __align__(16) u16 smem[16640];   // As[0:8192) Bs[8192:16384) T[0:16640)
  u16* As = smem;
  u16* Bs = smem + 8192;
  u16* T  = smem;                             // z==2 epilogue only (128 x 130)
  const int z = blockIdx.z;
  const u16* A = A0 + (long)z * 4194304;
  const u16* Bt = B0 + (long)z * 1048576;
  const int t = threadIdx.x, lane = t & 63, quad = lane >> 4, l16 = lane & 15;
  const int wave = t >> 6, wy = wave >> 1, wx = wave & 1;
  const int m0 = blockIdx.y * 128, n0 = blockIdx.x * 128;
  const int wbase = t & 192;
  f32x4 acc[4][4] = {};
  for (int k0 = 0; k0 < 1024; k0 += 64) {
    __syncthreads();
    #pragma unroll
    for (int i = 0; i < 4; ++i) {
      int sb = i * 256 + wbase;
      int s = sb + lane;
      int row = s >> 3, c = s & 7;
      int cs = c ^ (row & 7);              // source chunk for LDS pos c
      async16(As + sb * 8, A + (long)(m0 + row) * 1024 + k0 + cs * 8);
      async16(Bs + sb * 8, Bt + (long)(n0 + row) * 1024 + k0 + cs * 8);
    }
    __syncthreads();
    #pragma unroll
    for (int kk = 0; kk < 2; ++kk) {
      bf16x8 af[4], bfr[4];
      #pragma unroll
      for (int mt = 0; mt < 4; ++mt) {
        int row = wy * 64 + mt * 16 + l16;
        int pos = (kk * 4 + quad) ^ (row & 7);
        af[mt] = *(const bf16x8*)(As + row * 64 + pos * 8);
      }
      #pragma unroll
      for (int nt = 0; nt < 4; ++nt) {
        int row = wx * 64 + nt * 16 + l16;
        int pos = (kk * 4 + quad) ^ (row & 7);
        bfr[nt] = *(const bf16x8*)(Bs + row * 64 + pos * 8);
      }
      #pragma unroll
      for (int mt = 0; mt < 4; ++mt)
        #pragma unroll
        for (int nt = 0; nt < 4; ++nt)
          acc[mt][nt] = __builtin_amdgcn_mfma_f32_16x16x32_bf16(af[mt], bfr[nt], acc[mt][nt], 0, 0, 0);
    }
  }
  if (z < 2) {
    u16* C = C0 + (long)z * 4194304;
    const float scale = z ? 1.0f : scale0;
    #pragma unroll
    for (int mt = 0; mt < 4; ++mt)
      #pragma unroll
      for (int nt = 0; nt < 4; ++nt) {
        int col = n0 + wx * 64 + nt * 16 + l16;
        int row = m0 + wy * 64 + mt * 16 + quad * 4;
        uint32_t ua = pkbf(acc[mt][nt][0] * scale, acc[mt][nt][1] * scale);
        uint32_t ub = pkbf(acc[mt][nt][2] * scale, acc[mt][nt][3] * scale);
        C[(long)row * 1024 + col] = (u16)ua;
        C[(long)(row + 1) * 1024 + col] = (u16)(ua >> 16);
        C[(long)(row + 2) * 1024 + col] = (u16)ub;
        C[(long)(row + 3) * 1024 + col] = (u16)(ub >> 16);
      }
  } else {
    __syncthreads();  // all waves done reading As/Bs before T overlays them
    #pragma unroll
    for (int mt = 0; mt < 4; ++mt)
      #pragma unroll
      for (int nt = 0; nt < 4; ++nt) {
        int cc = wx * 64 + nt * 16 + l16;
        int rr = wy * 64 + mt * 16 + quad * 4;
        uint32_t ua = pkbf(acc[mt][nt][0], acc[mt][nt][1]);
        uint32_t ub = pkbf(acc[mt][nt][2], acc[mt][nt][3]);
        T[(rr + 0) * 130 + cc] = (u16)ua;
        T[(rr + 1) * 130 + cc] = (u16)(ua >> 16);
        T[(rr + 2) * 130 + cc] = (u16)ub;
        T[(rr + 3) * 130 + cc] = (u16)(ub >> 16);
      }
    __syncthreads();
    const int h0 = blockIdx.x * 2, bb = m0 >> 11, lb = m0 & 2047;
    #pragma unroll
    for (int i = 0; i < 8; ++i) {
      int s = t + i * 256;           // 0..2047 = 128 cols x 16 l-chunks
      int c = s >> 4, l0 = (s & 15) * 8;
      bf16x8 p;
      #pragma unroll
      for (int j = 0; j < 8; ++j) p[j] = (short)T[(l0 + j) * 130 + c];
      *(bf16x8*)(Vt + (long)(bb * 16 + h0 + (c >> 6)) * 131072 +
                 (long)(c & 63) * 2048 + lb + l0) = p;
    }
  }
}

// ---- out-proj GEMM: 128x64 tile, grid (16,32), async16, f32 out + bias ----
// (R2-verbatim)
__global__ __launch_bounds__(256) void k_gemm_out(const u16* __restrict__ A,
                                                  const u16* __restrict__ Bt,
                                                  float* __restrict__ C,
                                                  const float* __restrict__ bias) {
  __shared__ __align__(16) u16 As[128 * 32];
  __shared__ __align__(16) u16 Bs[64 * 32];
  const int t = threadIdx.x, lane = t & 63, quad = lane >> 4, l16 = lane & 15;
  const int wave = t >> 6;
  const int m0 = blockIdx.y * 128, n0 = blockIdx.x * 64;
  const int wbase = t & 192;
  f32x4 acc[2][4] = {};
  for (int k0 = 0; k0 < 1024; k0 += 32) {
    __syncthreads();
    #pragma unroll
    for (int i = 0; i < 2; ++i) {
      int sb = i * 256 + wbase;
      int s = sb + lane;
      int row = s >> 2, c = s & 3;
      async16(As + sb * 8, A + (long)(m0 + row) * 1024 + k0 + c * 8);
    }
    {
      int s = t;
      int row = s >> 2, c = s & 3;
      async16(Bs + wbase * 8, Bt + (long)(n0 + row) * 1024 + k0 + c * 8);
    }
    __syncthreads();
    bf16x8 af[2], bfr[4];
    #pragma unroll
    for (int mt = 0; mt < 2; ++mt)
      af[mt] = *(const bf16x8*)(As + (wave * 32 + mt * 16 + l16) * 32 + quad * 8);
    #pragma unroll
    for (int nt = 0; nt < 4; ++nt)
      bfr[nt] = *(const bf16x8*)(Bs + (nt * 16 + l16) * 32 + quad * 8);
    #pragma unroll
    for (int mt = 0; mt < 2; ++mt)
      #pragma unroll
      for (int nt = 0; nt < 4; ++nt)
        acc[mt][nt] = __builtin_amdgcn_mfma_f32_16x16x32_bf16(af[mt], bfr[nt], acc[mt][nt], 0, 0, 0);
  }
  #pragma unroll
  for (int mt = 0; mt < 2; ++mt)
    #pragma unroll
    for (int nt = 0; nt < 4; ++nt) {
      int col = n0 + nt * 16 + l16;
      #pragma unroll
      for (int r = 0; r < 4; ++r) {
        int row = m0 + wave * 32 + mt * 16 + quad * 4 + r;
        C[(long)row * 1024 + col] = acc[mt][nt][r] + bias[col];
      }
    }
}

// ------ flash attention: 32x32 MFMA + fully in-register softmax (m214) -----
// R2's grid (256 blocks, 512 thr), staging and 2-barrier schedule verbatim.
// mfma_f32_32x32x16_bf16: QK^T = mfma(K,Q) puts P[q=lane&31][kv=crow(r,hi)],
// crow=(r&3)+8*(r>>2)+4*hi, in regs. P->bf16 PV A-frags built in-register:
// per kv16-step s, target elem j needs reg (j&3)+8*(s&1)+4*hi_t of lane-half
// j>>2 -> 4 cvt_pk + 2 permlane32_swap per frag (T12 builtin, NOT raw asm —
// R7's asm form NaN'd). NO P LDS round-trip: LDS ops/wave/kt 28 -> 16, and
// the QK->exp2->P->PV chain is all register/VALU. lsum: 1 scalar/lane +
// shfl_xor(32) at the end. Derivation ref-checked offline with concrete kv
// values for both lane halves (s=0: {w0..w3} = {xA,yA,xB,yB} post-swap).
__global__ __launch_bounds__(512, 2) void k_flash(const u16* __restrict__ Qp,
                                                  const u16* __restrict__ Kp,
                                                  const u16* __restrict__ Vt,
                                                  u16* __restrict__ ctx) {
  __shared__ __align__(16) u16 qs[256 * 64];   // 32KB Q stage
  __shared__ __align__(16) u16 ks[64 * 72];    // K tile, padded rows
  __shared__ __align__(16) u16 vs[64 * 72];    // V^T tile, padded rows
  const int t = threadIdx.x, lane = t & 63, hi = lane >> 5, l32 = lane & 31;
  const int wave = t >> 6;                      // 0..7
  const int bh = blockIdx.x & 31, b = bh >> 4, h = bh & 15;
  const int q0 = (blockIdx.x >> 5) * 256;
  const long gkbase = (long)b * 2097152 + h * 64;
  const long gvbase = (long)bh * 131072;
  const int srow = t >> 3, sc = t & 7;          // staging: row 0..63, 16B chunk 0..7

  // ---- startup: Q via async16 (XOR swizzle), K/V tile 0 via regs ----
  {
    long gq = (long)(b * 2048 + q0) * 1024 + h * 64;
    #pragma unroll
    for (int i = 0; i < 4; ++i) {
      int s = i * 512 + t;
      int row = s >> 3, pos = s & 7, c = pos ^ (row & 7);
      async16(qs + (long)s * 8, Qp + gq + (long)row * 1024 + c * 8);
    }
  }
  bf16x8 kreg = *(const bf16x8*)(Kp + gkbase + (long)srow * 1024 + sc * 8);
  bf16x8 vreg = *(const bf16x8*)(Vt + gvbase + (long)srow * 2048 + sc * 8);
  __syncthreads();  // Q visible

  // Q B-frags: lane holds Q[q = wave*32+l32][d = sd*16 + hi*8 + j]
  bf16x8 qf[4];
  {
    int m = wave * 32 + l32;
    #pragma unroll
    for (int sd = 0; sd < 4; ++sd) {
      int pos = (sd * 2 + hi) ^ (m & 7);
      qf[sd] = *(const bf16x8*)(qs + m * 64 + pos * 8);
    }
  }
  *(bf16x8*)(ks + srow * 72 + sc * 8) = kreg;
  *(bf16x8*)(vs + srow * 72 + sc * 8) = vreg;
  __syncthreads();  // K/V tile 0 visible

  float ls = 0.0f;
  f32x16 o0 = {}, o1 = {};   // O[q][d] for d-blocks 0,1 (col = l32 = d)

  for (int kt = 0; kt < 32; ++kt) {
    // register prefetch of next K/V tile (in flight across this compute phase)
    if (kt < 31) {
      int kv0 = (kt + 1) * 64;
      kreg = *(const bf16x8*)(Kp + gkbase + (long)(kv0 + srow) * 1024 + sc * 8);
      vreg = *(const bf16x8*)(Vt + gvbase + kv0 + (long)srow * 2048 + sc * 8);
    }

    // K A-frags: lane = K[kv = c*32+l32][d = sd*16 + hi*8 + j]
    // V B-frags: lane = V^T[d = dblk*32+l32][kv = s*16 + hi*8 + j]
    bf16x8 kf0[4], kf1[4], vf0[4], vf1[4];
    #pragma unroll
    for (int sd = 0; sd < 4; ++sd) {
      kf0[sd] = *(const bf16x8*)(ks + (l32) * 72 + sd * 16 + hi * 8);
      kf1[sd] = *(const bf16x8*)(ks + (32 + l32) * 72 + sd * 16 + hi * 8);
      vf0[sd] = *(const bf16x8*)(vs + (l32) * 72 + sd * 16 + hi * 8);
      vf1[sd] = *(const bf16x8*)(vs + (32 + l32) * 72 + sd * 16 + hi * 8);
    }

    // S^T = K @ Q^T : p[c] holds S[q = l32][kv = crow(r,hi) + 32c]
    f32x16 p0 = {}, p1 = {};
    #pragma unroll
    for (int sd = 0; sd < 4; ++sd) {
      p0 = __builtin_amdgcn_mfma_f32_32x32x16_bf16(kf0[sd], qf[sd], p0, 0, 0, 0);
      p1 = __builtin_amdgcn_mfma_f32_32x32x16_bf16(kf1[sd], qf[sd], p1, 0, 0, 0);
    }
    // p = exp2(s); accumulate l
    #pragma unroll
    for (int r = 0; r < 16; ++r) {
      float e0 = __builtin_amdgcn_exp2f(p0[r]);
      float e1 = __builtin_amdgcn_exp2f(p1[r]);
      p0[r] = e0; p1[r] = e1;
      ls += e0 + e1;
    }
    // PV: per kv16-step s build A-frag in-register (cvt_pk + permlane32_swap)
    #pragma unroll
    for (int s = 0; s < 4; ++s) {
      const int oct = (s & 1) * 8;
      uint32_t xA, yA, xB, yB;
      if (s < 2) {
        xA = pkbf(p0[oct + 0], p0[oct + 1]);
        yA = pkbf(p0[oct + 2], p0[oct + 3]);
        xB = pkbf(p0[oct + 4], p0[oct + 5]);
        yB = pkbf(p0[oct + 6], p0[oct + 7]);
      } else {
        xA = pkbf(p1[oct + 0], p1[oct + 1]);
        yA = pkbf(p1[oct + 2], p1[oct + 3]);
        xB = pkbf(p1[oct + 4], p1[oct + 5]);
        yB = pkbf(p1[oct + 6], p1[oct + 7]);
      }
      swap32(xA, xB, hi);
      swap32(yA, yB, hi);
      union { uint32_t w[4]; bf16x8 v; } pa;
      pa.w[0] = xA; pa.w[1] = yA; pa.w[2] = xB; pa.w[3] = yB;
      o0 = __builtin_amdgcn_mfma_f32_32x32x16_bf16(pa.v, vf0[s], o0, 0, 0, 0);
      o1 = __builtin_amdgcn_mfma_f32_32x32x16_bf16(pa.v, vf1[s], o1, 0, 0, 0);
    }

    __syncthreads();  // all waves done reading ks/vs (and prefetch drained)
    if (kt < 31) {
      *(bf16x8*)(ks + srow * 72 + sc * 8) = kreg;
      *(bf16x8*)(vs + srow * 72 + sc * 8) = vreg;
    }
    __syncthreads();  // next tile visible
  }

  // final l: lane and lane^32 hold complementary kv-halves for q = l32
  ls += __shfl_xor(ls, 32);
  float linv = 1.0f / ls;                 // valid for q = l32 on every lane
  float li[16];
  #pragma unroll
  for (int r = 0; r < 16; ++r)
    li[r] = __shfl(linv, (r & 3) + 8 * (r >> 2) + 4 * hi);

  #pragma unroll
  for (int r = 0; r < 16; r += 2) {
    int q = q0 + wave * 32 + (r & 3) + 8 * (r >> 2) + 4 * hi;   // rows q, q+1
    long idx = (long)(b * 2048 + q) * 1024 + h * 64 + l32;
    uint32_t u0 = pkbf(o0[r] * li[r], o0[r + 1] * li[r + 1]);
    uint32_t u1 = pkbf(o1[r] * li[r], o1[r + 1] * li[r + 1]);
    ctx[idx]             = (u16)u0;
    ctx[idx + 1024]      = (u16)(u0 >> 16);
    ctx[idx + 32]        = (u16)u1;
    ctx[idx + 32 + 1024] = (u16)(u1 >> 16);
  }
}

extern "C" void kernel_launch(void* const* d_in, const int* in_sizes, int n_in,
                              void* d_out, int out_size, void* d_ws, size_t ws_size,
                              hipStream_t stream) {
  const float* query = (const float*)d_in[0];
  const float* key   = (const float*)d_in[1];
  const float* value = (const float*)d_in[2];
  const float* Wq    = (const float*)d_in[3];
  const float* Wk    = (const float*)d_in[4];
  const float* Wv    = (const float*)d_in[5];
  const float* out_w = (const float*)d_in[6];
  const float* out_b = (const float*)d_in[7];
  // d_in[8] = coupling: unused — per-head scalar bias is softmax-invariant.
  float* out = (float*)d_out;

  char* ws = (char*)d_ws;
  size_t off = 0;
  auto alloc = [&](size_t bytes) {
    void* p = ws + off;
    off += (bytes + 255) & ~(size_t)255;
    return p;
  };
  // qb,kb,vb contiguous (k_prep cast z-stride); wtq..wtv contiguous
  // (k_prep transpose z-stride); Qp,Kp contiguous (k_gemm_qkv z<2 stride).
  u16* qb  = (u16*)alloc(4096L * 1024 * 2);
  u16* kb  = (u16*)alloc(4096L * 1024 * 2);
  u16* vb  = (u16*)alloc(4096L * 1024 * 2);
  u16* wtq = (u16*)alloc(1024L * 1024 * 2);
  u16* wtk = (u16*)alloc(1024L * 1024 * 2);
  u16* wtv = (u16*)alloc(1024L * 1024 * 2);
  u16* wto = (u16*)alloc(1024L * 1024 * 2);
  u16* Qp  = (u16*)alloc(4096L * 1024 * 2);
  u16* Kp  = (u16*)alloc(4096L * 1024 * 2);
  u16* Vtb = (u16*)alloc(4096L * 1024 * 2);
  u16* ctx = qb;  // reuse: query-bf16 dead after Q projection
  (void)kb; (void)vb; (void)wtk; (void)wtv; (void)Kp;

  // fused pre-pass: input casts + all weight transposes in one launch
  k_prep<<<13312, 256, 0, stream>>>(Ptr3{query, key, value}, qb,
                                    Ptr3{Wq, Wk, Wv}, out_w, wtq, wto);

  // fused Q,K,V projections; z==2 writes Vt[bh][d][l] directly
  k_gemm_qkv<<<dim3(8, 32, 3), 256, 0, stream>>>(qb, wtq, Qp, Vtb, QSCALE);

  // attention: grid 256 = 8 q-tiles x 32 bh, bh in low 5 bits for XCD affinity
  k_flash<<<256, 512, 0, stream>>>(Qp, Kp, Vtb, ctx);

  // output projection + bias -> f32
  k_gemm_out<<<dim3(16, 32), 256, 0, stream>>>(ctx, wto, out, out_b);
}

// Round 9
// 218.055 us; speedup vs baseline: 1.0778x; 1.0251x over previous
//
#include <hip/hip_runtime.h>
#include <cstdint>

typedef uint16_t u16;
typedef __attribute__((ext_vector_type(8))) short bf16x8;
typedef __attribute__((ext_vector_type(4))) float f32x4;
typedef __attribute__((ext_vector_type(16))) float f32x16;

// 0.125 * log2(e): folded into Q projection so softmax is exp2(s) directly.
#define QSCALE 0.18033688011112042f

struct Ptr3 { const float* a; const float* b; const float* c; };

__device__ __forceinline__ u16 f2bf(float x) {
  union { float f; uint32_t u; } v; v.f = x;
  uint32_t r = (v.u + 0x7fffu + ((v.u >> 16) & 1u)) >> 16;
  return (u16)r;
}

// packed f32x2 -> bf16x2 (low = a, high = b). gfx950 has a HW instruction.
#if __has_builtin(__builtin_amdgcn_cvt_pk_bf16_f32)
typedef __bf16 bf2_t __attribute__((ext_vector_type(2)));
__device__ __forceinline__ uint32_t pkbf(float a, float b) {
  bf2_t v = __builtin_amdgcn_cvt_pk_bf16_f32(a, b);
  uint32_t u;
  __builtin_memcpy(&u, &v, 4);
  return u;
}
#else
__device__ __forceinline__ uint32_t pkbf(float a, float b) {
  return (uint32_t)f2bf(a) | ((uint32_t)f2bf(b) << 16);
}
#endif

// lane-half swap: a' = {a[0:31], b[0:31]}, b' = {a[32:63], b[32:63]}.
// R7 LESSON: raw-asm form NaN'd (compiler can't see cross-lane RMW of a
// 2x"+v" asm). Builtin form (T12 recipe) verified correct in R8.
#if __has_builtin(__builtin_amdgcn_permlane32_swap)
typedef __attribute__((ext_vector_type(2))) int i32x2;
__device__ __forceinline__ void swap32(uint32_t& a, uint32_t& b, int hi) {
  i32x2 r = __builtin_amdgcn_permlane32_swap((int)a, (int)b, false, false);
  a = (uint32_t)r.x;
  b = (uint32_t)r.y;
}
#else
__device__ __forceinline__ void swap32(uint32_t& a, uint32_t& b, int hi) {
  uint32_t ax = (uint32_t)__shfl_xor((int)a, 32);
  uint32_t bx = (uint32_t)__shfl_xor((int)b, 32);
  uint32_t na = hi ? bx : a;   // {a.lo, b.lo}
  uint32_t nb = hi ? b : ax;   // {a.hi, b.hi}
  a = na; b = nb;
}
#endif

// async global->LDS, 16B per lane. LDS dest is wave-uniform base + lane*16.
__device__ __forceinline__ void async16(void* lds, const void* g) {
  __builtin_amdgcn_global_load_lds((const __attribute__((address_space(1))) void*)g,
                                   (__attribute__((address_space(3))) void*)lds, 16, 0, 0);
}

// -------- fused pre-pass: input casts (12288 blocks) + weight transposes ---
// (R2-verbatim)
__global__ __launch_bounds__(256) void k_prep(Ptr3 in, u16* __restrict__ out,
                                              Ptr3 w, const float* __restrict__ ow,
                                              u16* __restrict__ wt, u16* __restrict__ wto) {
  __shared__ u16 tile[64 * 65];
  const int t = threadIdx.x;
  const int bx = blockIdx.x;
  if (bx < 12288) {
    int z = bx >> 12;
    int i = (bx & 4095) * 256 + t;
    const float* p = z == 0 ? in.a : (z == 1 ? in.b : in.c);
    float4 v = ((const float4*)p)[i];
    uint2 o2;
    o2.x = pkbf(v.x, v.y);
    o2.y = pkbf(v.z, v.w);
    *(uint2*)(out + (long)z * 4194304 + (long)i * 4) = o2;
    return;
  }
  const int b2 = bx - 12288;
  const float* src;
  long in_base, out_base;
  int rstr, r0, c0;
  u16* outp;
  if (b2 < 768) {
    int z = b2 >> 4;
    r0 = (b2 & 15) * 64; c0 = 0;
    src = (z < 16) ? w.a : (z < 32 ? w.b : w.c);
    in_base = (long)(z & 15) * 65536;
    out_base = (long)z * 65536;
    rstr = 64; outp = wt;
  } else {
    int idx = b2 - 768;
    r0 = (idx >> 4) * 64; c0 = (idx & 15) * 64;
    src = ow; in_base = 0; out_base = 0;
    rstr = 1024; outp = wto;
  }
  for (int e = t; e < 4096; e += 256) {
    int rr = e >> 6, cc = e & 63;
    tile[rr * 65 + cc] = f2bf(src[in_base + (long)(r0 + rr) * rstr + c0 + cc]);
  }
  __syncthreads();
  for (int s = t; s < 512; s += 256) {
    int cc = s >> 3, r8 = (s & 7) << 3;
    bf16x8 p;
    #pragma unroll
    for (int j = 0; j < 8; ++j) p[j] = (short)tile[(r8 + j) * 65 + cc];
    *(bf16x8*)(outp + out_base + (long)(c0 + cc) * 1024 + r0 + r8) = p;
  }
}

// ---------------- fused QKV GEMM: 128x128 tile, BK=64, grid (32,8,3) -------
// R9: grid orientation swapped (was (8,32,3)). Linear id = m + 32n + 256z so
// XCD = m&7: all 8 n-blocks sharing an A-panel land on ONE XCD -> A-panel
// fetched once per L2 (was: XCD = n -> every XCD pulled the full 8MB A).
// Per-z L2-miss 66 -> ~24MB. Kernel body identical; m comes from blockIdx.x.
__global__ __launch_bounds__(256) void k_gemm_qkv(const u16* __restrict__ A0,
                                                  const u16* __restrict__ B0,
                                                  u16* __restrict__ C0,
                                                  u16* __restrict__ Vt, float scale0) {
  __shared__ __align__(16) u16 smem[16640];   // As[0:8192) Bs[8192:16384) T[0:16640)
  u16* As = smem;
  u16* Bs = smem + 8192;
  u16* T  = smem;                             // z==2 epilogue only (128 x 130)
  const int z = blockIdx.z;
  const u16* A = A0 + (long)z * 4194304;
  const u16* Bt = B0 + (long)z * 1048576;
  const int t = threadIdx.x, lane = t & 63, quad = lane >> 4, l16 = lane & 15;
  const int wave = t >> 6, wy = wave >> 1, wx = wave & 1;
  const int m0 = blockIdx.x * 128, n0 = blockIdx.y * 128;
  const int wbase = t & 192;
  f32x4 acc[4][4] = {};
  for (int k0 = 0; k0 < 1024; k0 += 64) {
    __syncthreads();
    #pragma unroll
    for (int i = 0; i < 4; ++i) {
      int sb = i * 256 + wbase;
      int s = sb + lane;
      int row = s >> 3, c = s & 7;
      int cs = c ^ (row & 7);              // source chunk for LDS pos c
      async16(As + sb * 8, A + (long)(m0 + row) * 1024 + k0 + cs * 8);
      async16(Bs + sb * 8, Bt + (long)(n0 + row) * 1024 + k0 + cs * 8);
    }
    __syncthreads();
    #pragma unroll
    for (int kk = 0; kk < 2; ++kk) {
      bf16x8 af[4], bfr[4];
      #pragma unroll
      for (int mt = 0; mt < 4; ++mt) {
        int row = wy * 64 + mt * 16 + l16;
        int pos = (kk * 4 + quad) ^ (row & 7);
        af[mt] = *(const bf16x8*)(As + row * 64 + pos * 8);
      }
      #pragma unroll
      for (int nt = 0; nt < 4; ++nt) {
        int row = wx * 64 + nt * 16 + l16;
        int pos = (kk * 4 + quad) ^ (row & 7);
        bfr[nt] = *(const bf16x8*)(Bs + row * 64 + pos * 8);
      }
      #pragma unroll
      for (int mt = 0; mt < 4; ++mt)
        #pragma unroll
        for (int nt = 0; nt < 4; ++nt)
          acc[mt][nt] = __builtin_amdgcn_mfma_f32_16x16x32_bf16(af[mt], bfr[nt], acc[mt][nt], 0, 0, 0);
    }
  }
  if (z < 2) {
    u16* C = C0 + (long)z * 4194304;
    const float scale = z ? 1.0f : scale0;
    #pragma unroll
    for (int mt = 0; mt < 4; ++mt)
      #pragma unroll
      for (int nt = 0; nt < 4; ++nt) {
        int col = n0 + wx * 64 + nt * 16 + l16;
        int row = m0 + wy * 64 + mt * 16 + quad * 4;
        uint32_t ua = pkbf(acc[mt][nt][0] * scale, acc[mt][nt][1] * scale);
        uint32_t ub = pkbf(acc[mt][nt][2] * scale, acc[mt][nt][3] * scale);
        C[(long)row * 1024 + col] = (u16)ua;
        C[(long)(row + 1) * 1024 + col] = (u16)(ua >> 16);
        C[(long)(row + 2) * 1024 + col] = (u16)ub;
        C[(long)(row + 3) * 1024 + col] = (u16)(ub >> 16);
      }
  } else {
    __syncthreads();  // all waves done reading As/Bs before T overlays them
    #pragma unroll
    for (int mt = 0; mt < 4; ++mt)
      #pragma unroll
      for (int nt = 0; nt < 4; ++nt) {
        int cc = wx * 64 + nt * 16 + l16;
        int rr = wy * 64 + mt * 16 + quad * 4;
        uint32_t ua = pkbf(acc[mt][nt][0], acc[mt][nt][1]);
        uint32_t ub = pkbf(acc[mt][nt][2], acc[mt][nt][3]);
        T[(rr + 0) * 130 + cc] = (u16)ua;
        T[(rr + 1) * 130 + cc] = (u16)(ua >> 16);
        T[(rr + 2) * 130 + cc] = (u16)ub;
        T[(rr + 3) * 130 + cc] = (u16)(ub >> 16);
      }
    __syncthreads();
    const int h0 = blockIdx.y * 2, bb = m0 >> 11, lb = m0 & 2047;
    #pragma unroll
    for (int i = 0; i < 8; ++i) {
      int s = t + i * 256;           // 0..2047 = 128 cols x 16 l-chunks
      int c = s >> 4, l0 = (s & 15) * 8;
      bf16x8 p;
      #pragma unroll
      for (int j = 0; j < 8; ++j) p[j] = (short)T[(l0 + j) * 130 + c];
      *(bf16x8*)(Vt + (long)(bb * 16 + h0 + (c >> 6)) * 131072 +
                 (long)(c & 63) * 2048 + lb + l0) = p;
    }
  }
}

// ---- out-proj GEMM: 128x64 tile, grid (32,16), async16, f32 out + bias ----
// R9: grid orientation swapped (was (16,32)) for the same XCD-affinity
// reason: XCD = m&7 -> ctx panel fetched once per L2; wto (2MB) replicated.
__global__ __launch_bounds__(256) void k_gemm_out(const u16* __restrict__ A,
                                                  const u16* __restrict__ Bt,
                                                  float* __restrict__ C,
                                                  const float* __restrict__ bias) {
  __shared__ __align__(16) u16 As[128 * 32];
  __shared__ __align__(16) u16 Bs[64 * 32];
  const int t = threadIdx.x, lane = t & 63, quad = lane >> 4, l16 = lane & 15;
  const int wave = t >> 6;
  const int m0 = blockIdx.x * 128, n0 = blockIdx.y * 64;
  const int wbase = t & 192;
  f32x4 acc[2][4] = {};
  for (int k0 = 0; k0 < 1024; k0 += 32) {
    __syncthreads();
    #pragma unroll
    for (int i = 0; i < 2; ++i) {
      int sb = i * 256 + wbase;
      int s = sb + lane;
      int row = s >> 2, c = s & 3;
      async16(As + sb * 8, A + (long)(m0 + row) * 1024 + k0 + c * 8);
    }
    {
      int s = t;
      int row = s >> 2, c = s & 3;
      async16(Bs + wbase * 8, Bt + (long)(n0 + row) * 1024 + k0 + c * 8);
    }
    __syncthreads();
    bf16x8 af[2], bfr[4];
    #pragma unroll
    for (int mt = 0; mt < 2; ++mt)
      af[mt] = *(const bf16x8*)(As + (wave * 32 + mt * 16 + l16) * 32 + quad * 8);
    #pragma unroll
    for (int nt = 0; nt < 4; ++nt)
      bfr[nt] = *(const bf16x8*)(Bs + (nt * 16 + l16) * 32 + quad * 8);
    #pragma unroll
    for (int mt = 0; mt < 2; ++mt)
      #pragma unroll
      for (int nt = 0; nt < 4; ++nt)
        acc[mt][nt] = __builtin_amdgcn_mfma_f32_16x16x32_bf16(af[mt], bfr[nt], acc[mt][nt], 0, 0, 0);
  }
  #pragma unroll
  for (int mt = 0; mt < 2; ++mt)
    #pragma unroll
    for (int nt = 0; nt < 4; ++nt) {
      int col = n0 + nt * 16 + l16;
      #pragma unroll
      for (int r = 0; r < 4; ++r) {
        int row = m0 + wave * 32 + mt * 16 + quad * 4 + r;
        C[(long)row * 1024 + col] = acc[mt][nt][r] + bias[col];
      }
    }
}

// ------ flash attention: 32x32 MFMA + fully in-register softmax (R8) -------
// PROVEN 49.7us (R8): conflicts 7.34M -> 33K, MfmaUtil 26. Do not touch.
__global__ __launch_bounds__(512, 2) void k_flash(const u16* __restrict__ Qp,
                                                  const u16* __restrict__ Kp,
                                                  const u16* __restrict__ Vt,
                                                  u16* __restrict__ ctx) {
  __shared__ __align__(16) u16 qs[256 * 64];   // 32KB Q stage
  __shared__ __align__(16) u16 ks[64 * 72];    // K tile, padded rows
  __shared__ __align__(16) u16 vs[64 * 72];    // V^T tile, padded rows
  const int t = threadIdx.x, lane = t & 63, hi = lane >> 5, l32 = lane & 31;
  const int wave = t >> 6;                      // 0..7
  const int bh = blockIdx.x & 31, b = bh >> 4, h = bh & 15;
  const int q0 = (blockIdx.x >> 5) * 256;
  const long gkbase = (long)b * 2097152 + h * 64;
  const long gvbase = (long)bh * 131072;
  const int srow = t >> 3, sc = t & 7;          // staging: row 0..63, 16B chunk 0..7

  // ---- startup: Q via async16 (XOR swizzle), K/V tile 0 via regs ----
  {
    long gq = (long)(b * 2048 + q0) * 1024 + h * 64;
    #pragma unroll
    for (int i = 0; i < 4; ++i) {
      int s = i * 512 + t;
      int row = s >> 3, pos = s & 7, c = pos ^ (row & 7);
      async16(qs + (long)s * 8, Qp + gq + (long)row * 1024 + c * 8);
    }
  }
  bf16x8 kreg = *(const bf16x8*)(Kp + gkbase + (long)srow * 1024 + sc * 8);
  bf16x8 vreg = *(const bf16x8*)(Vt + gvbase + (long)srow * 2048 + sc * 8);
  __syncthreads();  // Q visible

  // Q B-frags: lane holds Q[q = wave*32+l32][d = sd*16 + hi*8 + j]
  bf16x8 qf[4];
  {
    int m = wave * 32 + l32;
    #pragma unroll
    for (int sd = 0; sd < 4; ++sd) {
      int pos = (sd * 2 + hi) ^ (m & 7);
      qf[sd] = *(const bf16x8*)(qs + m * 64 + pos * 8);
    }
  }
  *(bf16x8*)(ks + srow * 72 + sc * 8) = kreg;
  *(bf16x8*)(vs + srow * 72 + sc * 8) = vreg;
  __syncthreads();  // K/V tile 0 visible

  float ls = 0.0f;
  f32x16 o0 = {}, o1 = {};   // O[q][d] for d-blocks 0,1 (col = l32 = d)

  for (int kt = 0; kt < 32; ++kt) {
    // register prefetch of next K/V tile (in flight across this compute phase)
    if (kt < 31) {
      int kv0 = (kt + 1) * 64;
      kreg = *(const bf16x8*)(Kp + gkbase + (long)(kv0 + srow) * 1024 + sc * 8);
      vreg = *(const bf16x8*)(Vt + gvbase + kv0 + (long)srow * 2048 + sc * 8);
    }

    // K A-frags: lane = K[kv = c*32+l32][d = sd*16 + hi*8 + j]
    // V B-frags: lane = V^T[d = dblk*32+l32][kv = s*16 + hi*8 + j]
    bf16x8 kf0[4], kf1[4], vf0[4], vf1[4];
    #pragma unroll
    for (int sd = 0; sd < 4; ++sd) {
      kf0[sd] = *(const bf16x8*)(ks + (l32) * 72 + sd * 16 + hi * 8);
      kf1[sd] = *(const bf16x8*)(ks + (32 + l32) * 72 + sd * 16 + hi * 8);
      vf0[sd] = *(const bf16x8*)(vs + (l32) * 72 + sd * 16 + hi * 8);
      vf1[sd] = *(const bf16x8*)(vs + (32 + l32) * 72 + sd * 16 + hi * 8);
    }

    // S^T = K @ Q^T : p[c] holds S[q = l32][kv = crow(r,hi) + 32c]
    f32x16 p0 = {}, p1 = {};
    #pragma unroll
    for (int sd = 0; sd < 4; ++sd) {
      p0 = __builtin_amdgcn_mfma_f32_32x32x16_bf16(kf0[sd], qf[sd], p0, 0, 0, 0);
      p1 = __builtin_amdgcn_mfma_f32_32x32x16_bf16(kf1[sd], qf[sd], p1, 0, 0, 0);
    }
    // p = exp2(s); accumulate l
    #pragma unroll
    for (int r = 0; r < 16; ++r) {
      float e0 = __builtin_amdgcn_exp2f(p0[r]);
      float e1 = __builtin_amdgcn_exp2f(p1[r]);
      p0[r] = e0; p1[r] = e1;
      ls += e0 + e1;
    }
    // PV: per kv16-step s build A-frag in-register (cvt_pk + permlane32_swap)
    #pragma unroll
    for (int s = 0; s < 4; ++s) {
      const int oct = (s & 1) * 8;
      uint32_t xA, yA, xB, yB;
      if (s < 2) {
        xA = pkbf(p0[oct + 0], p0[oct + 1]);
        yA = pkbf(p0[oct + 2], p0[oct + 3]);
        xB = pkbf(p0[oct + 4], p0[oct + 5]);
        yB = pkbf(p0[oct + 6], p0[oct + 7]);
      } else {
        xA = pkbf(p1[oct + 0], p1[oct + 1]);
        yA = pkbf(p1[oct + 2], p1[oct + 3]);
        xB = pkbf(p1[oct + 4], p1[oct + 5]);
        yB = pkbf(p1[oct + 6], p1[oct + 7]);
      }
      swap32(xA, xB, hi);
      swap32(yA, yB, hi);
      union { uint32_t w[4]; bf16x8 v; } pa;
      pa.w[0] = xA; pa.w[1] = yA; pa.w[2] = xB; pa.w[3] = yB;
      o0 = __builtin_amdgcn_mfma_f32_32x32x16_bf16(pa.v, vf0[s], o0, 0, 0, 0);
      o1 = __builtin_amdgcn_mfma_f32_32x32x16_bf16(pa.v, vf1[s], o1, 0, 0, 0);
    }

    __syncthreads();  // all waves done reading ks/vs (and prefetch drained)
    if (kt < 31) {
      *(bf16x8*)(ks + srow * 72 + sc * 8) = kreg;
      *(bf16x8*)(vs + srow * 72 + sc * 8) = vreg;
    }
    __syncthreads();  // next tile visible
  }

  // final l: lane and lane^32 hold complementary kv-halves for q = l32
  ls += __shfl_xor(ls, 32);
  float linv = 1.0f / ls;                 // valid for q = l32 on every lane
  float li[16];
  #pragma unroll
  for (int r = 0; r < 16; ++r)
    li[r] = __shfl(linv, (r & 3) + 8 * (r >> 2) + 4 * hi);

  #pragma unroll
  for (int r = 0; r < 16; r += 2) {
    int q = q0 + wave * 32 + (r & 3) + 8 * (r >> 2) + 4 * hi;   // rows q, q+1
    long idx = (long)(b * 2048 + q) * 1024 + h * 64 + l32;
    uint32_t u0 = pkbf(o0[r] * li[r], o0[r + 1] * li[r + 1]);
    uint32_t u1 = pkbf(o1[r] * li[r], o1[r + 1] * li[r + 1]);
    ctx[idx]             = (u16)u0;
    ctx[idx + 1024]      = (u16)(u0 >> 16);
    ctx[idx + 32]        = (u16)u1;
    ctx[idx + 32 + 1024] = (u16)(u1 >> 16);
  }
}

extern "C" void kernel_launch(void* const* d_in, const int* in_sizes, int n_in,
                              void* d_out, int out_size, void* d_ws, size_t ws_size,
                              hipStream_t stream) {
  const float* query = (const float*)d_in[0];
  const float* key   = (const float*)d_in[1];
  const float* value = (const float*)d_in[2];
  const float* Wq    = (const float*)d_in[3];
  const float* Wk    = (const float*)d_in[4];
  const float* Wv    = (const float*)d_in[5];
  const float* out_w = (const float*)d_in[6];
  const float* out_b = (const float*)d_in[7];
  // d_in[8] = coupling: unused — per-head scalar bias is softmax-invariant.
  float* out = (float*)d_out;

  char* ws = (char*)d_ws;
  size_t off = 0;
  auto alloc = [&](size_t bytes) {
    void* p = ws + off;
    off += (bytes + 255) & ~(size_t)255;
    return p;
  };
  // qb,kb,vb contiguous (k_prep cast z-stride); wtq..wtv contiguous
  // (k_prep transpose z-stride); Qp,Kp contiguous (k_gemm_qkv z<2 stride).
  u16* qb  = (u16*)alloc(4096L * 1024 * 2);
  u16* kb  = (u16*)alloc(4096L * 1024 * 2);
  u16* vb  = (u16*)alloc(4096L * 1024 * 2);
  u16* wtq = (u16*)alloc(1024L * 1024 * 2);
  u16* wtk = (u16*)alloc(1024L * 1024 * 2);
  u16* wtv = (u16*)alloc(1024L * 1024 * 2);
  u16* wto = (u16*)alloc(1024L * 1024 * 2);
  u16* Qp  = (u16*)alloc(4096L * 1024 * 2);
  u16* Kp  = (u16*)alloc(4096L * 1024 * 2);
  u16* Vtb = (u16*)alloc(4096L * 1024 * 2);
  u16* ctx = qb;  // reuse: query-bf16 dead after Q projection
  (void)kb; (void)vb; (void)wtk; (void)wtv; (void)Kp;

  // fused pre-pass: input casts + all weight transposes in one launch
  k_prep<<<13312, 256, 0, stream>>>(Ptr3{query, key, value}, qb,
                                    Ptr3{Wq, Wk, Wv}, out_w, wtq, wto);

  // fused Q,K,V projections; z==2 writes Vt[bh][d][l] directly.
  // grid (32,8,3): XCD = m&7 -> A-panel XCD affinity (R9).
  k_gemm_qkv<<<dim3(32, 8, 3), 256, 0, stream>>>(qb, wtq, Qp, Vtb, QSCALE);

  // attention: grid 256 = 8 q-tiles x 32 bh, bh in low 5 bits for XCD affinity
  k_flash<<<256, 512, 0, stream>>>(Qp, Kp, Vtb, ctx);

  // output projection + bias -> f32. grid (32,16): XCD = m&7 (R9).
  k_gemm_out<<<dim3(32, 16), 256, 0, stream>>>(ctx, wto, out, out_b);
}